// Round 7
// baseline (453.767 us; speedup 1.0000x reference)
//
#include <hip/hip_runtime.h>
#include <hip/hip_bf16.h>
#include <math.h>
#include <stdint.h>

typedef __hip_bfloat16 bf16;
typedef __attribute__((ext_vector_type(8))) short short8;
typedef __attribute__((ext_vector_type(4))) float f32x4;

#define B_SZ   16
#define HH     56
#define WW2    56
#define L_TOK  3136
#define C_DIM  192
#define NH_    6
#define DH     32
#define WS_    7
#define SS_    3
#define NW     49
#define NWIN   64
#define BWIN   (B_SZ*NWIN)  // 1024
#define TOK    (BWIN*NW)    // 50176
#define HID_   768

__device__ __forceinline__ float b2f(bf16 x){ return __bfloat162float(x); }
__device__ __forceinline__ bf16  f2b(float x){ return __float2bfloat16(x); }
__device__ __forceinline__ short f2bs(float x){ bf16 h = __float2bfloat16(x); return *reinterpret_cast<short*>(&h); }

// async global->LDS, 16B per lane; LDS dest = wave-uniform base + lane*16 (CK cast pattern)
__device__ __forceinline__ void gload16(const void* g, void* l) {
    __builtin_amdgcn_global_load_lds(
        (const __attribute__((address_space(1))) void*)(uintptr_t)g,
        (__attribute__((address_space(3))) void*)(uintptr_t)l, 16, 0, 0);
}

__device__ __forceinline__ float wave_sum64(float v){
    #pragma unroll
    for (int off = 32; off > 0; off >>= 1) v += __shfl_xor(v, off, 64);
    return v;
}

// ---------------------------------------------------------------------------
// LN1(se), LN1(de), copy(co) + cyclic shift + window partition.
// ---------------------------------------------------------------------------
__global__ void prep_kernel(const float* __restrict__ se, const float* __restrict__ de,
                            const float* __restrict__ co,
                            const float* __restrict__ g1s, const float* __restrict__ b1s,
                            const float* __restrict__ g1d, const float* __restrict__ b1d,
                            bf16* __restrict__ sw, bf16* __restrict__ dw, bf16* __restrict__ cw)
{
    int t   = blockIdx.x;
    int tid = threadIdx.x;
    int b_  = t / NW, n = t % NW;
    int b   = b_ / NWIN, w = b_ % NWIN;
    int wh  = w >> 3, wwi = w & 7;
    int i   = n / WS_, j = n % WS_;
    int hs  = wh*WS_ + i, ws = wwi*WS_ + j;
    int hsrc = hs + SS_; if (hsrc >= HH)  hsrc -= HH;
    int wsrc = ws + SS_; if (wsrc >= WW2) wsrc -= WW2;
    long src = ((long)(b*L_TOK + hsrc*WW2 + wsrc)) * C_DIM;
    long dst = (long)t * C_DIM;

    {
        float x0 = se[src+tid], x1 = se[src+tid+64], x2 = se[src+tid+128];
        float s  = wave_sum64(x0+x1+x2);
        float ss = wave_sum64(x0*x0 + x1*x1 + x2*x2);
        float mean = s * (1.0f/192.0f);
        float var  = ss * (1.0f/192.0f) - mean*mean;
        float rstd = rsqrtf(var + 1e-5f);
        sw[dst+tid]     = f2b((x0-mean)*rstd*g1s[tid]     + b1s[tid]);
        sw[dst+tid+64]  = f2b((x1-mean)*rstd*g1s[tid+64]  + b1s[tid+64]);
        sw[dst+tid+128] = f2b((x2-mean)*rstd*g1s[tid+128] + b1s[tid+128]);
    }
    {
        float x0 = de[src+tid], x1 = de[src+tid+64], x2 = de[src+tid+128];
        float s  = wave_sum64(x0+x1+x2);
        float ss = wave_sum64(x0*x0 + x1*x1 + x2*x2);
        float mean = s * (1.0f/192.0f);
        float var  = ss * (1.0f/192.0f) - mean*mean;
        float rstd = rsqrtf(var + 1e-5f);
        dw[dst+tid]     = f2b((x0-mean)*rstd*g1d[tid]     + b1d[tid]);
        dw[dst+tid+64]  = f2b((x1-mean)*rstd*g1d[tid+64]  + b1d[tid+64]);
        dw[dst+tid+128] = f2b((x2-mean)*rstd*g1d[tid+128] + b1d[tid+128]);
    }
    cw[dst+tid]     = f2b(co[src+tid]);
    cw[dst+tid+64]  = f2b(co[src+tid+64]);
    cw[dst+tid+128] = f2b(co[src+tid+128]);
}

// ---------------------------------------------------------------------------
// Weight pre-convert: fp32 [K][N] -> bf16 MFMA-B-fragment order.
// ---------------------------------------------------------------------------
__global__ __launch_bounds__(256)
void wconv(const float* w0,const float* w1,const float* w2,const float* w3,const float* w4,
           const float* w5,const float* w6,const float* w7,const float* w8, short* dst)
{
    const float* src; int K, N; long doff;
    switch (blockIdx.y) {
      case 0: src=w0; K=384; N=192; doff=0;      break;
      case 1: src=w1; K=384; N=192; doff=73728;  break;
      case 2: src=w2; K=192; N=384; doff=147456; break;
      case 3: src=w3; K=192; N=192; doff=221184; break;
      case 4: src=w4; K=192; N=192; doff=258048; break;
      case 5: src=w5; K=192; N=768; doff=294912; break;
      case 6: src=w6; K=768; N=192; doff=442368; break;
      case 7: src=w7; K=192; N=768; doff=589824; break;
      default:src=w8; K=768; N=192; doff=737280; break;
    }
    int nblk = (K>>5)*(N>>6);
    int bid = blockIdx.x;
    if (bid >= nblk) return;
    int kb = bid / (N>>6), nb = bid % (N>>6);
    __shared__ float tile[32][65];
    int tid = threadIdx.x;
    #pragma unroll
    for (int it = 0; it < 8; ++it) {
        int idx = tid + it*256;
        int r = idx >> 6, c = idx & 63;
        tile[r][c] = src[(long)(kb*32 + r)*N + nb*64 + c];
    }
    __syncthreads();
    int lane = tid & 63, nl = tid >> 6;
    short8 v;
    #pragma unroll
    for (int j = 0; j < 8; ++j)
        v[j] = f2bs(tile[(lane>>4)*8 + j][nl*16 + (lane&15)]);
    long nig = (long)nb*4 + nl;
    *(short8*)(dst + doff + (((long)kb*(N>>4) + nig)*64 + lane)*8) = v;
}

// ---------------------------------------------------------------------------
// fgemm2: C[M x Nn] = A[M x K](bf16) @ Wfrag(bf16 frag-order) + bias(fp32)
// tile 128x192, 6 waves (2x3), double-buffered LDS via global_load_lds(16B),
// 2-phase pipeline: STAGE(t+1) issued before MFMA(t); barrier drains vmcnt.
// ---------------------------------------------------------------------------
template<int MODE>
__global__ __launch_bounds__(384)
void fgemm2(const bf16* __restrict__ A1, const bf16* __restrict__ A2, int K1, int K,
            const short* __restrict__ wf, const float* __restrict__ bias, int Nn,
            bf16* __restrict__ out, bf16* __restrict__ out2,
            const float* __restrict__ res_src, const bf16* __restrict__ prj,
            int t0, float* __restrict__ dout)
{
    __shared__ short AsF[2][8][64][8];   // dbuf x m-tile x lane x 8 = 16 KB
    int tid = threadIdx.x;
    int wid = tid >> 6, lane = tid & 63;
    int wr = (wid >= 3) ? 1 : 0, wc = wid - wr*3;
    int l15 = lane & 15, g = lane >> 4;
    int row0 = blockIdx.x * 128, col0 = blockIdx.y * 192;
    const int ntiles = Nn >> 4;

    f32x4 acc[4][4];
    #pragma unroll
    for (int m = 0; m < 4; m++)
        #pragma unroll
        for (int n = 0; n < 4; n++)
            acc[m][n] = (f32x4){0.f,0.f,0.f,0.f};

    int nk = K >> 5;
    // stage: slice a covers rows a*16..a*16+15; lane -> (row a*16+l15, kseg g)
    // LDS dest wave-uniform &AsF[buf][a][0][0]; HW adds lane*16B.
    #define STAGE(buf_, k0_) {                                                   \
        int colk = (k0_) + (g << 3);                                             \
        const bf16* asrc = (colk < K1) ? A1 : A2;                                \
        int kc = (colk < K1) ? colk : colk - K1;                                 \
        gload16(asrc + (long)(row0 + wid*16 + l15)*K1 + kc,                      \
                &AsF[buf_][wid][0][0]);                                          \
        if (wid < 2)                                                             \
            gload16(asrc + (long)(row0 + (6+wid)*16 + l15)*K1 + kc,              \
                    &AsF[buf_][6+wid][0][0]);                                    \
    }

    STAGE(0, 0);
    __syncthreads();
    for (int t = 0; t < nk; ++t) {
        int buf = t & 1;
        if (t + 1 < nk) STAGE(buf ^ 1, (t+1) << 5);
        short8 af[4], bf4[4];
        #pragma unroll
        for (int m = 0; m < 4; m++) af[m] = *((short8*)&AsF[buf][wr*4 + m][lane][0]);
        const short* wbase = wf + (((long)t*ntiles + (col0>>4) + wc*4)*64 + lane)*8;
        #pragma unroll
        for (int n = 0; n < 4; n++) bf4[n] = *(const short8*)(wbase + n*512);
        #pragma unroll
        for (int m = 0; m < 4; m++)
            #pragma unroll
            for (int n = 0; n < 4; n++)
                acc[m][n] = __builtin_amdgcn_mfma_f32_16x16x32_bf16(af[m], bf4[n], acc[m][n], 0, 0, 0);
        __syncthreads();   // drains vmcnt(0): STAGE(t+1) landed; safe to swap
    }
    #undef STAGE

    // epilogue: D row = 16m + 4g + rr (within wave-row), col = 16n2 + l15
    #pragma unroll
    for (int m = 0; m < 4; m++) {
        #pragma unroll
        for (int rr = 0; rr < 4; rr++) {
            int t = row0 + wr*64 + m*16 + g*4 + rr;
            if (MODE == 4) {
                int tg = t0 + t;
                int b = tg / L_TOK, l = tg % L_TOK;
                int h = l / WW2, wcol = l % WW2;
                int hp = h - SS_;    if (hp < 0) hp += HH;
                int wp = wcol - SS_; if (wp < 0) wp += WW2;
                int b_ = b*NWIN + (hp/WS_)*8 + (wp/WS_);
                int n = (hp%WS_)*WS_ + (wp%WS_);
                long wsoff = ((long)b_*NW + n)*C_DIM;
                long goff  = (long)tg*C_DIM;
                #pragma unroll
                for (int n2 = 0; n2 < 4; n2++) {
                    int oc = col0 + wc*64 + n2*16 + l15;
                    float v = acc[m][n2][rr] + bias[oc];
                    dout[goff + oc] = res_src[goff + oc] + b2f(prj[wsoff + oc]) + v;
                }
            } else {
                #pragma unroll
                for (int n2 = 0; n2 < 4; n2++) {
                    int oc = col0 + wc*64 + n2*16 + l15;
                    float v = acc[m][n2][rr] + bias[oc];
                    if (MODE == 0) {
                        out[(long)t*Nn + oc] = f2b(v);
                    } else if (MODE == 1) {
                        int b_ = t / NW, n = t % NW;
                        if (oc < C_DIM) {
                            int head = oc >> 5, d = oc & 31;
                            out[(((long)b_*NH_ + head)*NW + n)*DH + d] = f2b(v * 0.17677669529663687f);
                        } else {
                            int och = oc - C_DIM;
                            int head = och >> 5, d = och & 31;
                            out2[(((long)b_*NH_ + head)*NW + n)*DH + d] = f2b(v);
                        }
                    } else if (MODE == 2) {
                        int b_ = t / NW, n = t % NW;
                        int head = oc >> 5, d = oc & 31;
                        out[(((long)b_*NH_ + head)*NW + n)*DH + d] = f2b(v);
                    } else { // MODE 3
                        float g2 = 0.5f * v * (1.0f + erff(v * 0.70710678118654752f));
                        out[(long)t*Nn + oc] = f2b(g2);
                    }
                }
            }
        }
    }
}

// ---------------------------------------------------------------------------
// mgemm (fallback when ws too small for frag weights): 128x64 tile, 4 waves.
// ---------------------------------------------------------------------------
#define BM 128
#define BN 64

template<int MODE>
__global__ __launch_bounds__(256)
void mgemm(const bf16* __restrict__ A1, const bf16* __restrict__ A2, int K1, int K,
           const float* __restrict__ W, const float* __restrict__ bias, int Nn,
           bf16* __restrict__ out, bf16* __restrict__ out2,
           const float* __restrict__ res_src, const bf16* __restrict__ prj,
           int t0, float* __restrict__ dout)
{
    __shared__ short AsF[8][64][8];
    __shared__ short BsF[4][64][8];
    int tid  = threadIdx.x;
    int wid  = tid >> 6, lane = tid & 63;
    int wr   = wid >> 1, wc = wid & 1;
    int row0 = blockIdx.x * BM, col0 = blockIdx.y * BN;

    f32x4 acc[4][2];
    #pragma unroll
    for (int m = 0; m < 4; m++)
        #pragma unroll
        for (int n = 0; n < 2; n++)
            acc[m][n] = (f32x4){0.f, 0.f, 0.f, 0.f};

    int ar = tid >> 2, akseg = tid & 3;
    int bc = tid & 63, bk8 = tid >> 6;

    for (int k0 = 0; k0 < K; k0 += 32) {
        {
            int col = k0 + akseg*8;
            const bf16* asrc = (col < K1) ? A1 : A2;
            int akc = (col < K1) ? col : col - K1;
            #pragma unroll
            for (int rr = 0; rr < 2; rr++) {
                int r = ar + rr*64;
                short8 av = *(const short8*)(asrc + (long)(row0 + r)*K1 + akc);
                *((short8*)&AsF[r >> 4][(r & 15) + (akseg << 4)][0]) = av;
            }
        }
        {
            short8 bv;
            #pragma unroll
            for (int j = 0; j < 8; j++)
                bv[j] = f2bs(W[(long)(k0 + bk8*8 + j)*Nn + col0 + bc]);
            *((short8*)&BsF[bc >> 4][(bc & 15) + (bk8 << 4)][0]) = bv;
        }
        __syncthreads();
        short8 af[4], bfr[2];
        #pragma unroll
        for (int m = 0; m < 4; m++) af[m]  = *((short8*)&AsF[wr*4 + m][lane][0]);
        #pragma unroll
        for (int n = 0; n < 2; n++) bfr[n] = *((short8*)&BsF[wc*2 + n][lane][0]);
        #pragma unroll
        for (int m = 0; m < 4; m++)
            #pragma unroll
            for (int n = 0; n < 2; n++)
                acc[m][n] = __builtin_amdgcn_mfma_f32_16x16x32_bf16(af[m], bfr[n], acc[m][n], 0, 0, 0);
        __syncthreads();
    }

    #pragma unroll
    for (int m = 0; m < 4; m++) {
        #pragma unroll
        for (int rr = 0; rr < 4; rr++) {
            int t = row0 + wr*64 + m*16 + (lane >> 4)*4 + rr;
            if (MODE == 4) {
                int tg = t0 + t;
                int b = tg / L_TOK, l = tg % L_TOK;
                int h = l / WW2, wcol = l % WW2;
                int hp = h - SS_;    if (hp < 0) hp += HH;
                int wp = wcol - SS_; if (wp < 0) wp += WW2;
                int b_ = b*NWIN + (hp/WS_)*8 + (wp/WS_);
                int n  = (hp%WS_)*WS_ + (wp%WS_);
                long wsoff = ((long)b_*NW + n)*C_DIM;
                long goff  = (long)tg*C_DIM;
                #pragma unroll
                for (int n2 = 0; n2 < 2; n2++) {
                    int oc = col0 + wc*32 + n2*16 + (lane & 15);
                    float v = acc[m][n2][rr] + bias[oc];
                    dout[goff + oc] = res_src[goff + oc] + b2f(prj[wsoff + oc]) + v;
                }
            } else {
                #pragma unroll
                for (int n2 = 0; n2 < 2; n2++) {
                    int oc = col0 + wc*32 + n2*16 + (lane & 15);
                    float v = acc[m][n2][rr] + bias[oc];
                    if (MODE == 0) {
                        out[(long)t*Nn + oc] = f2b(v);
                    } else if (MODE == 1) {
                        int b_ = t / NW, n = t % NW;
                        if (oc < C_DIM) {
                            int head = oc >> 5, d = oc & 31;
                            out[(((long)b_*NH_ + head)*NW + n)*DH + d] = f2b(v * 0.17677669529663687f);
                        } else {
                            int och = oc - C_DIM;
                            int head = och >> 5, d = och & 31;
                            out2[(((long)b_*NH_ + head)*NW + n)*DH + d] = f2b(v);
                        }
                    } else if (MODE == 2) {
                        int b_ = t / NW, n = t % NW;
                        int head = oc >> 5, d = oc & 31;
                        out[(((long)b_*NH_ + head)*NW + n)*DH + d] = f2b(v);
                    } else {
                        float g2 = 0.5f * v * (1.0f + erff(v * 0.70710678118654752f));
                        out[(long)t*Nn + oc] = f2b(g2);
                    }
                }
            }
        }
    }
}

// ---------------------------------------------------------------------------
// MFMA attention: 1 wave per (window,head), 2 waves/block.
// ---------------------------------------------------------------------------
#define PSTR 72
#define VSTR 72

__global__ __launch_bounds__(128)
void attn_mfma(const bf16* __restrict__ qb, const bf16* __restrict__ kb,
               const bf16* __restrict__ vse, const bf16* __restrict__ vde,
               const float* __restrict__ rpb,
               bf16* __restrict__ ose, bf16* __restrict__ ode)
{
    __shared__ float rpbs[169*NH_];
    __shared__ short P[2][64][PSTR];
    __shared__ short VTs[2][32][VSTR];
    __shared__ short VTd[2][32][VSTR];
    int tid = threadIdx.x, wid = tid >> 6, lane = tid & 63;
    for (int i = tid; i < 169*NH_; i += 128) rpbs[i] = rpb[i];
    __syncthreads();

    int bh = blockIdx.x*2 + wid;
    int b_ = bh / NH_, head = bh % NH_;
    int w = b_ & (NWIN-1);
    int wh = w >> 3, ww = w & 7;
    long base = (long)bh * (NW*DH);
    int l15 = lane & 15, g = lane >> 4;

    short8 qf[4], kf[4];
    #pragma unroll
    for (int mi = 0; mi < 4; mi++) {
        int r = l15 + 16*mi; if (r > 48) r = 48;
        qf[mi] = *(const short8*)(qb + base + r*DH + 8*g);
    }
    #pragma unroll
    for (int ni = 0; ni < 4; ni++) {
        int r = l15 + 16*ni; if (r > 48) r = 48;
        kf[ni] = *(const short8*)(kb + base + r*DH + 8*g);
    }

    f32x4 sA[4][4];
    #pragma unroll
    for (int mi = 0; mi < 4; mi++)
        #pragma unroll
        for (int ni = 0; ni < 4; ni++)
            sA[mi][ni] = (f32x4){0.f,0.f,0.f,0.f};
    #pragma unroll
    for (int mi = 0; mi < 4; mi++)
        #pragma unroll
        for (int ni = 0; ni < 4; ni++)
            sA[mi][ni] = __builtin_amdgcn_mfma_f32_16x16x32_bf16(qf[mi], kf[ni], sA[mi][ni], 0, 0, 0);

    {
        int j0 = lane >> 2, seg = lane & 3;
        #pragma unroll
        for (int it = 0; it < 4; ++it) {
            int j = j0 + 16*it;
            short8 a = {0,0,0,0,0,0,0,0}, bv = {0,0,0,0,0,0,0,0};
            if (j < NW) {
                a  = *(const short8*)(vse + base + j*DH + seg*8);
                bv = *(const short8*)(vde + base + j*DH + seg*8);
            }
            #pragma unroll
            for (int s2 = 0; s2 < 8; ++s2) {
                VTs[wid][seg*8 + s2][j] = a[s2];
                VTd[wid][seg*8 + s2][j] = bv[s2];
            }
        }
    }

    int jv[4], j7r_[4], j7c_[4], jrh_[4], jrc_[4];
    #pragma unroll
    for (int ni = 0; ni < 4; ++ni) {
        int j = 16*ni + l15;
        jv[ni] = (j < NW);
        int a = (j*37) >> 8; int c = j - 7*a;
        j7r_[ni] = a; j7c_[ni] = c;
        int jh = wh*7 + a, jw = ww*7 + c;
        jrh_[ni] = (jh >= 49) + (jh >= 53);
        jrc_[ni] = (jw >= 49) + (jw >= 53);
    }

    #pragma unroll
    for (int mi = 0; mi < 4; mi++) {
        #pragma unroll
        for (int rr = 0; rr < 4; rr++) {
            int i = 16*mi + 4*g + rr;
            int iv = (i < NW);
            int i7r = (i*37) >> 8; int i7c = i - 7*i7r;
            int ih = wh*7 + i7r, iw = ww*7 + i7c;
            int irh = (ih >= 49) + (ih >= 53), irc = (iw >= 49) + (iw >= 53);
            float sv[4];
            #pragma unroll
            for (int ni = 0; ni < 4; ni++) {
                if (iv && jv[ni]) {
                    int ri = (i7r - j7r_[ni] + 6)*13 + (i7c - j7c_[ni] + 6);
                    float msk = (irh == jrh_[ni] && irc == jrc_[ni]) ? 0.f : -100.f;
                    sv[ni] = sA[mi][ni][rr] + rpbs[ri*NH_ + head] + msk;
                } else {
                    sv[ni] = -1e30f;
                }
            }
            float mx = fmaxf(fmaxf(sv[0], sv[1]), fmaxf(sv[2], sv[3]));
            mx = fmaxf(mx, __shfl_xor(mx, 1));
            mx = fmaxf(mx, __shfl_xor(mx, 2));
            mx = fmaxf(mx, __shfl_xor(mx, 4));
            mx = fmaxf(mx, __shfl_xor(mx, 8));
            float e[4], sum = 0.f;
            #pragma unroll
            for (int ni = 0; ni < 4; ni++) { e[ni] = __expf(sv[ni] - mx); sum += e[ni]; }
            sum += __shfl_xor(sum, 1);
            sum += __shfl_xor(sum, 2);
            sum += __shfl_xor(sum, 4);
            sum += __shfl_xor(sum, 8);
            float inv = 1.0f / sum;
            #pragma unroll
            for (int ni = 0; ni < 4; ni++)
                P[wid][i][16*ni + l15] = f2bs(e[ni] * inv);
        }
    }
    __syncthreads();

    f32x4 o1[4][2], o2[4][2];
    #pragma unroll
    for (int mi = 0; mi < 4; mi++)
        #pragma unroll
        for (int di = 0; di < 2; di++) {
            o1[mi][di] = (f32x4){0.f,0.f,0.f,0.f};
            o2[mi][di] = (f32x4){0.f,0.f,0.f,0.f};
        }
    #pragma unroll
    for (int mi = 0; mi < 4; mi++) {
        #pragma unroll
        for (int kk = 0; kk < 2; kk++) {
            short8 ap = *((short8*)&P[wid][16*mi + l15][kk*32 + 8*g]);
            #pragma unroll
            for (int di = 0; di < 2; di++) {
                short8 bv1 = *((short8*)&VTs[wid][16*di + l15][kk*32 + 8*g]);
                o1[mi][di] = __builtin_amdgcn_mfma_f32_16x16x32_bf16(ap, bv1, o1[mi][di], 0, 0, 0);
                short8 bv2 = *((short8*)&VTd[wid][16*di + l15][kk*32 + 8*g]);
                o2[mi][di] = __builtin_amdgcn_mfma_f32_16x16x32_bf16(ap, bv2, o2[mi][di], 0, 0, 0);
            }
        }
    }

    #pragma unroll
    for (int mi = 0; mi < 4; mi++) {
        #pragma unroll
        for (int rr = 0; rr < 4; rr++) {
            int i = 16*mi + 4*g + rr;
            if (i < NW) {
                long ob = ((long)b_*NW + i)*C_DIM + head*DH;
                #pragma unroll
                for (int di = 0; di < 2; di++) {
                    ose[ob + 16*di + l15] = f2b(o1[mi][di][rr]);
                    ode[ob + 16*di + l15] = f2b(o2[mi][di][rr]);
                }
            }
        }
    }
}

// ---------------------------------------------------------------------------
// Fused window-reverse + un-shift + residual + LN2 (xn only).
// ---------------------------------------------------------------------------
__global__ void resid_ln2_kernel(const float* __restrict__ se, const float* __restrict__ de,
                                 const bf16* __restrict__ pse, const bf16* __restrict__ pde,
                                 const float* __restrict__ g2s, const float* __restrict__ bb2s,
                                 const float* __restrict__ g2d, const float* __restrict__ bb2d,
                                 bf16* __restrict__ xns, bf16* __restrict__ xnd)
{
    int t = blockIdx.x, tid = threadIdx.x;
    int b = t / L_TOK, l = t % L_TOK;
    int h = l / WW2, wc = l % WW2;
    int hp = h - SS_;  if (hp < 0) hp += HH;
    int wp = wc - SS_; if (wp < 0) wp += WW2;
    int b_ = b*NWIN + (hp/WS_)*8 + (wp/WS_);
    int n  = (hp%WS_)*WS_ + (wp%WS_);
    long wsoff = ((long)b_*NW + n)*C_DIM;
    long off   = (long)t*C_DIM;
    {
        float x0 = se[off+tid]     + b2f(pse[wsoff+tid]);
        float x1 = se[off+tid+64]  + b2f(pse[wsoff+tid+64]);
        float x2 = se[off+tid+128] + b2f(pse[wsoff+tid+128]);
        float s  = wave_sum64(x0+x1+x2);
        float ss = wave_sum64(x0*x0 + x1*x1 + x2*x2);
        float mean = s * (1.0f/192.0f);
        float var  = ss * (1.0f/192.0f) - mean*mean;
        float rstd = rsqrtf(var + 1e-5f);
        xns[off+tid]     = f2b((x0-mean)*rstd*g2s[tid]     + bb2s[tid]);
        xns[off+tid+64]  = f2b((x1-mean)*rstd*g2s[tid+64]  + bb2s[tid+64]);
        xns[off+tid+128] = f2b((x2-mean)*rstd*g2s[tid+128] + bb2s[tid+128]);
    }
    {
        float x0 = de[off+tid]     + b2f(pde[wsoff+tid]);
        float x1 = de[off+tid+64]  + b2f(pde[wsoff+tid+64]);
        float x2 = de[off+tid+128] + b2f(pde[wsoff+tid+128]);
        float s  = wave_sum64(x0+x1+x2);
        float ss = wave_sum64(x0*x0 + x1*x1 + x2*x2);
        float mean = s * (1.0f/192.0f);
        float var  = ss * (1.0f/192.0f) - mean*mean;
        float rstd = rsqrtf(var + 1e-5f);
        xnd[off+tid]     = f2b((x0-mean)*rstd*g2d[tid]     + bb2d[tid]);
        xnd[off+tid+64]  = f2b((x1-mean)*rstd*g2d[tid+64]  + bb2d[tid+64]);
        xnd[off+tid+128] = f2b((x2-mean)*rstd*g2d[tid+128] + bb2d[tid+128]);
    }
}

// ---------------------------------------------------------------------------
extern "C" void kernel_launch(void* const* d_in, const int* in_sizes, int n_in,
                              void* d_out, int out_size, void* d_ws, size_t ws_size,
                              hipStream_t stream)
{
    const float* se     = (const float*)d_in[0];
    const float* de     = (const float*)d_in[1];
    const float* co     = (const float*)d_in[2];
    const float* n1se_g = (const float*)d_in[4];
    const float* n1se_b = (const float*)d_in[5];
    const float* n1de_g = (const float*)d_in[6];
    const float* n1de_b = (const float*)d_in[7];
    const float* rpb    = (const float*)d_in[8];
    const float* vse_w  = (const float*)d_in[9];
    const float* vse_b  = (const float*)d_in[10];
    const float* vde_w  = (const float*)d_in[11];
    const float* vde_b  = (const float*)d_in[12];
    const float* qk_w   = (const float*)d_in[13];
    const float* qk_b   = (const float*)d_in[14];
    const float* pse_w  = (const float*)d_in[15];
    const float* pse_b  = (const float*)d_in[16];
    const float* pde_w  = (const float*)d_in[17];
    const float* pde_b  = (const float*)d_in[18];
    const float* n2se_g = (const float*)d_in[19];
    const float* n2se_b = (const float*)d_in[20];
    const float* n2de_g = (const float*)d_in[21];
    const float* n2de_b = (const float*)d_in[22];
    const float* mse_w1 = (const float*)d_in[23];
    const float* mse_b1 = (const float*)d_in[24];
    const float* mse_w2 = (const float*)d_in[25];
    const float* mse_b2 = (const float*)d_in[26];
    const float* mde_w1 = (const float*)d_in[27];
    const float* mde_b1 = (const float*)d_in[28];
    const float* mde_w2 = (const float*)d_in[29];
    const float* mde_b2 = (const float*)d_in[30];

    char* ws = (char*)d_ws;
    const size_t U = (size_t)TOK * C_DIM * 2;   // 19,267,584 bytes
    bf16* sw  = (bf16*)(ws + 0*U);
    bf16* dw  = (bf16*)(ws + 1*U);
    bf16* cw  = (bf16*)(ws + 2*U);
    bf16* vse = (bf16*)(ws + 3*U);
    bf16* vde = (bf16*)(ws + 4*U);
    bf16* ode = (bf16*)(ws + 5*U);
    bf16* qb  = (bf16*)(ws + 0*U);
    bf16* kb  = (bf16*)(ws + 1*U);
    bf16* ose = (bf16*)(ws + 2*U);
    bf16* pse = (bf16*)(ws + 0*U);
    bf16* pde = (bf16*)(ws + 1*U);
    bf16* xns = (bf16*)(ws + 2*U);
    bf16* xnd = (bf16*)(ws + 3*U);
    bf16* hid = (bf16*)(ws + 4*U);
    short* wfb = (short*)(ws + 6*U);            // 884,736 bf16 = 1.73 MB

    const bool frag = (ws_size >= 6*U + 884736ull*2ull);
    float* dout = (float*)d_out;
    const int CH = TOK/2;

    if (frag)
        wconv<<<dim3(72, 9), 256, 0, stream>>>(vse_w, vde_w, qk_w, pse_w, pde_w,
                                               mse_w1, mse_w2, mde_w1, mde_w2, wfb);
    prep_kernel<<<TOK, 64, 0, stream>>>(se, de, co, n1se_g, n1se_b, n1de_g, n1de_b, sw, dw, cw);

    if (frag) {
        fgemm2<2><<<dim3(TOK/128, 1), 384, 0, stream>>>(sw, cw, C_DIM, 2*C_DIM, wfb + 0,      vse_b, C_DIM,
                                                        vse, nullptr, nullptr, nullptr, 0, nullptr);
        fgemm2<2><<<dim3(TOK/128, 1), 384, 0, stream>>>(dw, cw, C_DIM, 2*C_DIM, wfb + 73728,  vde_b, C_DIM,
                                                        vde, nullptr, nullptr, nullptr, 0, nullptr);
        fgemm2<1><<<dim3(TOK/128, 2), 384, 0, stream>>>(cw, cw, C_DIM, C_DIM,   wfb + 147456, qk_b, 384,
                                                        qb, kb, nullptr, nullptr, 0, nullptr);
    } else {
        mgemm<2><<<dim3(TOK/BM, C_DIM/BN), 256, 0, stream>>>(sw, cw, C_DIM, 2*C_DIM, vse_w, vse_b, C_DIM,
                                                             vse, nullptr, nullptr, nullptr, 0, nullptr);
        mgemm<2><<<dim3(TOK/BM, C_DIM/BN), 256, 0, stream>>>(dw, cw, C_DIM, 2*C_DIM, vde_w, vde_b, C_DIM,
                                                             vde, nullptr, nullptr, nullptr, 0, nullptr);
        mgemm<1><<<dim3(TOK/BM, 384/BN), 256, 0, stream>>>(cw, cw, C_DIM, C_DIM, qk_w, qk_b, 384,
                                                           qb, kb, nullptr, nullptr, 0, nullptr);
    }

    attn_mfma<<<BWIN*NH_/2, 128, 0, stream>>>(qb, kb, vse, vde, rpb, ose, ode);

    if (frag) {
        fgemm2<0><<<dim3(TOK/128, 1), 384, 0, stream>>>(ose, ose, C_DIM, C_DIM, wfb + 221184, pse_b, C_DIM,
                                                        pse, nullptr, nullptr, nullptr, 0, nullptr);
        fgemm2<0><<<dim3(TOK/128, 1), 384, 0, stream>>>(ode, ode, C_DIM, C_DIM, wfb + 258048, pde_b, C_DIM,
                                                        pde, nullptr, nullptr, nullptr, 0, nullptr);
    } else {
        mgemm<0><<<dim3(TOK/BM, C_DIM/BN), 256, 0, stream>>>(ose, ose, C_DIM, C_DIM, pse_w, pse_b, C_DIM,
                                                             pse, nullptr, nullptr, nullptr, 0, nullptr);
        mgemm<0><<<dim3(TOK/BM, C_DIM/BN), 256, 0, stream>>>(ode, ode, C_DIM, C_DIM, pde_w, pde_b, C_DIM,
                                                             pde, nullptr, nullptr, nullptr, 0, nullptr);
    }

    resid_ln2_kernel<<<TOK, 64, 0, stream>>>(se, de, pse, pde,
                                             n2se_g, n2se_b, n2de_g, n2de_b, xns, xnd);

    if (frag) {
        for (int c0 = 0; c0 < 2; c0++) {
            int t0 = c0 * CH;
            fgemm2<3><<<dim3(CH/128, 4), 384, 0, stream>>>(xns + (long)t0*C_DIM, xns + (long)t0*C_DIM,
                                                           C_DIM, C_DIM, wfb + 294912, mse_b1, HID_,
                                                           hid, nullptr, nullptr, nullptr, 0, nullptr);
            fgemm2<4><<<dim3(CH/128, 1), 384, 0, stream>>>(hid, hid, HID_, HID_, wfb + 442368, mse_b2, C_DIM,
                                                           nullptr, nullptr, se, pse, t0, dout);
        }
        for (int c0 = 0; c0 < 2; c0++) {
            int t0 = c0 * CH;
            fgemm2<3><<<dim3(CH/128, 4), 384, 0, stream>>>(xnd + (long)t0*C_DIM, xnd + (long)t0*C_DIM,
                                                           C_DIM, C_DIM, wfb + 589824, mde_b1, HID_,
                                                           hid, nullptr, nullptr, nullptr, 0, nullptr);
            fgemm2<4><<<dim3(CH/128, 1), 384, 0, stream>>>(hid, hid, HID_, HID_, wfb + 737280, mde_b2, C_DIM,
                                                           nullptr, nullptr, de, pde, t0,
                                                           dout + (size_t)TOK*C_DIM);
        }
    } else {
        for (int c0 = 0; c0 < 2; c0++) {
            int t0 = c0 * CH;
            mgemm<3><<<dim3(CH/BM, HID_/BN), 256, 0, stream>>>(xns + (long)t0*C_DIM, xns + (long)t0*C_DIM,
                                                               C_DIM, C_DIM, mse_w1, mse_b1, HID_,
                                                               hid, nullptr, nullptr, nullptr, 0, nullptr);
            mgemm<4><<<dim3(CH/BM, C_DIM/BN), 256, 0, stream>>>(hid, hid, HID_, HID_, mse_w2, mse_b2, C_DIM,
                                                                nullptr, nullptr, se, pse, t0, dout);
        }
        for (int c0 = 0; c0 < 2; c0++) {
            int t0 = c0 * CH;
            mgemm<3><<<dim3(CH/BM, HID_/BN), 256, 0, stream>>>(xnd + (long)t0*C_DIM, xnd + (long)t0*C_DIM,
                                                               C_DIM, C_DIM, mde_w1, mde_b1, HID_,
                                                               hid, nullptr, nullptr, nullptr, 0, nullptr);
            mgemm<4><<<dim3(CH/BM, C_DIM/BN), 256, 0, stream>>>(hid, hid, HID_, HID_, mde_w2, mde_b2, C_DIM,
                                                                nullptr, nullptr, de, pde, t0,
                                                                dout + (size_t)TOK*C_DIM);
        }
    }
}

// Round 8
// 443.826 us; speedup vs baseline: 1.0224x; 1.0224x over previous
//
#include <hip/hip_runtime.h>
#include <hip/hip_bf16.h>
#include <math.h>
#include <stdint.h>

typedef __hip_bfloat16 bf16;
typedef __attribute__((ext_vector_type(8))) short short8;
typedef __attribute__((ext_vector_type(4))) float f32x4;

#define B_SZ   16
#define HH     56
#define WW2    56
#define L_TOK  3136
#define C_DIM  192
#define NH_    6
#define DH     32
#define WS_    7
#define SS_    3
#define NW     49
#define NWIN   64
#define BWIN   (B_SZ*NWIN)  // 1024
#define TOK    (BWIN*NW)    // 50176
#define HID_   768

__device__ __forceinline__ float b2f(bf16 x){ return __bfloat162float(x); }
__device__ __forceinline__ bf16  f2b(float x){ return __float2bfloat16(x); }
__device__ __forceinline__ short f2bs(float x){ bf16 h = __float2bfloat16(x); return *reinterpret_cast<short*>(&h); }

// async global->LDS, 16B per lane; LDS dest = wave-uniform base + lane*16
__device__ __forceinline__ void gload16(const void* g, void* l) {
    __builtin_amdgcn_global_load_lds(
        (const __attribute__((address_space(1))) void*)(uintptr_t)g,
        (__attribute__((address_space(3))) void*)(uintptr_t)l, 16, 0, 0);
}

__device__ __forceinline__ float wave_sum64(float v){
    #pragma unroll
    for (int off = 32; off > 0; off >>= 1) v += __shfl_xor(v, off, 64);
    return v;
}

// ---------------------------------------------------------------------------
// LN1(se), LN1(de), copy(co) + cyclic shift + window partition.
// ---------------------------------------------------------------------------
__global__ void prep_kernel(const float* __restrict__ se, const float* __restrict__ de,
                            const float* __restrict__ co,
                            const float* __restrict__ g1s, const float* __restrict__ b1s,
                            const float* __restrict__ g1d, const float* __restrict__ b1d,
                            bf16* __restrict__ sw, bf16* __restrict__ dw, bf16* __restrict__ cw)
{
    int t   = blockIdx.x;
    int tid = threadIdx.x;
    int b_  = t / NW, n = t % NW;
    int b   = b_ / NWIN, w = b_ % NWIN;
    int wh  = w >> 3, wwi = w & 7;
    int i   = n / WS_, j = n % WS_;
    int hs  = wh*WS_ + i, ws = wwi*WS_ + j;
    int hsrc = hs + SS_; if (hsrc >= HH)  hsrc -= HH;
    int wsrc = ws + SS_; if (wsrc >= WW2) wsrc -= WW2;
    long src = ((long)(b*L_TOK + hsrc*WW2 + wsrc)) * C_DIM;
    long dst = (long)t * C_DIM;

    {
        float x0 = se[src+tid], x1 = se[src+tid+64], x2 = se[src+tid+128];
        float s  = wave_sum64(x0+x1+x2);
        float ss = wave_sum64(x0*x0 + x1*x1 + x2*x2);
        float mean = s * (1.0f/192.0f);
        float var  = ss * (1.0f/192.0f) - mean*mean;
        float rstd = rsqrtf(var + 1e-5f);
        sw[dst+tid]     = f2b((x0-mean)*rstd*g1s[tid]     + b1s[tid]);
        sw[dst+tid+64]  = f2b((x1-mean)*rstd*g1s[tid+64]  + b1s[tid+64]);
        sw[dst+tid+128] = f2b((x2-mean)*rstd*g1s[tid+128] + b1s[tid+128]);
    }
    {
        float x0 = de[src+tid], x1 = de[src+tid+64], x2 = de[src+tid+128];
        float s  = wave_sum64(x0+x1+x2);
        float ss = wave_sum64(x0*x0 + x1*x1 + x2*x2);
        float mean = s * (1.0f/192.0f);
        float var  = ss * (1.0f/192.0f) - mean*mean;
        float rstd = rsqrtf(var + 1e-5f);
        dw[dst+tid]     = f2b((x0-mean)*rstd*g1d[tid]     + b1d[tid]);
        dw[dst+tid+64]  = f2b((x1-mean)*rstd*g1d[tid+64]  + b1d[tid+64]);
        dw[dst+tid+128] = f2b((x2-mean)*rstd*g1d[tid+128] + b1d[tid+128]);
    }
    cw[dst+tid]     = f2b(co[src+tid]);
    cw[dst+tid+64]  = f2b(co[src+tid+64]);
    cw[dst+tid+128] = f2b(co[src+tid+128]);
}

// ---------------------------------------------------------------------------
// Weight pre-convert: fp32 [K][N] -> bf16 MFMA-B-fragment order.
// ---------------------------------------------------------------------------
__global__ __launch_bounds__(256)
void wconv(const float* w0,const float* w1,const float* w2,const float* w3,const float* w4,
           const float* w5,const float* w6,const float* w7,const float* w8, short* dst)
{
    const float* src; int K, N; long doff;
    switch (blockIdx.y) {
      case 0: src=w0; K=384; N=192; doff=0;      break;
      case 1: src=w1; K=384; N=192; doff=73728;  break;
      case 2: src=w2; K=192; N=384; doff=147456; break;
      case 3: src=w3; K=192; N=192; doff=221184; break;
      case 4: src=w4; K=192; N=192; doff=258048; break;
      case 5: src=w5; K=192; N=768; doff=294912; break;
      case 6: src=w6; K=768; N=192; doff=442368; break;
      case 7: src=w7; K=192; N=768; doff=589824; break;
      default:src=w8; K=768; N=192; doff=737280; break;
    }
    int nblk = (K>>5)*(N>>6);
    int bid = blockIdx.x;
    if (bid >= nblk) return;
    int kb = bid / (N>>6), nb = bid % (N>>6);
    __shared__ float tile[32][65];
    int tid = threadIdx.x;
    #pragma unroll
    for (int it = 0; it < 8; ++it) {
        int idx = tid + it*256;
        int r = idx >> 6, c = idx & 63;
        tile[r][c] = src[(long)(kb*32 + r)*N + nb*64 + c];
    }
    __syncthreads();
    int lane = tid & 63, nl = tid >> 6;
    short8 v;
    #pragma unroll
    for (int j = 0; j < 8; ++j)
        v[j] = f2bs(tile[(lane>>4)*8 + j][nl*16 + (lane&15)]);
    long nig = (long)nb*4 + nl;
    *(short8*)(dst + doff + (((long)kb*(N>>4) + nig)*64 + lane)*8) = v;
}

// ---------------------------------------------------------------------------
// fgemm2: C = A(bf16) @ Wfrag(bf16) + bias. tile 128x192, 6 waves,
// dbuf LDS via global_load_lds. DUAL: blockIdx.x >= nxblk -> second stream.
// ---------------------------------------------------------------------------
template<int MODE, bool DUAL>
__global__ __launch_bounds__(384)
void fgemm2(const bf16* __restrict__ A1, const bf16* __restrict__ A2, int K1, int K,
            const short* __restrict__ wf, const float* __restrict__ bias, int Nn,
            bf16* __restrict__ out, bf16* __restrict__ out2,
            const bf16* __restrict__ A1b, const bf16* __restrict__ A2b,
            const short* __restrict__ wfB, const float* __restrict__ biasB,
            bf16* __restrict__ outB, int nxblk)
{
    __shared__ short AsF[2][8][64][8];
    int tid = threadIdx.x;
    int wid = tid >> 6, lane = tid & 63;
    int wr = (wid >= 3) ? 1 : 0, wc = wid - wr*3;
    int l15 = lane & 15, g = lane >> 4;

    int bx = blockIdx.x;
    const bf16 *A1p = A1, *A2p = A2; const short* wfp = wf;
    const float* biasp = bias; bf16* outp = out;
    if (DUAL && bx >= nxblk) {
        bx -= nxblk; A1p = A1b; A2p = A2b; wfp = wfB; biasp = biasB; outp = outB;
    }
    int row0 = bx * 128, col0 = blockIdx.y * 192;
    const int ntiles = Nn >> 4;

    f32x4 acc[4][4];
    #pragma unroll
    for (int m = 0; m < 4; m++)
        #pragma unroll
        for (int n = 0; n < 4; n++)
            acc[m][n] = (f32x4){0.f,0.f,0.f,0.f};

    int nk = K >> 5;
    #define STAGE(buf_, k0_) {                                                   \
        int colk = (k0_) + (g << 3);                                             \
        const bf16* asrc = (colk < K1) ? A1p : A2p;                              \
        int kc = (colk < K1) ? colk : colk - K1;                                 \
        gload16(asrc + (long)(row0 + wid*16 + l15)*K1 + kc,                      \
                &AsF[buf_][wid][0][0]);                                          \
        if (wid < 2)                                                             \
            gload16(asrc + (long)(row0 + (6+wid)*16 + l15)*K1 + kc,              \
                    &AsF[buf_][6+wid][0][0]);                                    \
    }

    STAGE(0, 0);
    __syncthreads();
    for (int t = 0; t < nk; ++t) {
        int buf = t & 1;
        if (t + 1 < nk) STAGE(buf ^ 1, (t+1) << 5);
        short8 af[4], bf4[4];
        #pragma unroll
        for (int m = 0; m < 4; m++) af[m] = *((short8*)&AsF[buf][wr*4 + m][lane][0]);
        const short* wbase = wfp + (((long)t*ntiles + (col0>>4) + wc*4)*64 + lane)*8;
        #pragma unroll
        for (int n = 0; n < 4; n++) bf4[n] = *(const short8*)(wbase + n*512);
        #pragma unroll
        for (int m = 0; m < 4; m++)
            #pragma unroll
            for (int n = 0; n < 4; n++)
                acc[m][n] = __builtin_amdgcn_mfma_f32_16x16x32_bf16(af[m], bf4[n], acc[m][n], 0, 0, 0);
        __syncthreads();
    }
    #undef STAGE

    #pragma unroll
    for (int m = 0; m < 4; m++) {
        #pragma unroll
        for (int rr = 0; rr < 4; rr++) {
            int t = row0 + wr*64 + m*16 + g*4 + rr;
            #pragma unroll
            for (int n2 = 0; n2 < 4; n2++) {
                int oc = col0 + wc*64 + n2*16 + l15;
                float v = acc[m][n2][rr] + biasp[oc];
                if (MODE == 0) {
                    outp[(long)t*Nn + oc] = f2b(v);
                } else if (MODE == 1) {
                    int b_ = t / NW, n = t % NW;
                    if (oc < C_DIM) {
                        int head = oc >> 5, d = oc & 31;
                        outp[(((long)b_*NH_ + head)*NW + n)*DH + d] = f2b(v * 0.17677669529663687f);
                    } else {
                        int och = oc - C_DIM;
                        int head = och >> 5, d = och & 31;
                        out2[(((long)b_*NH_ + head)*NW + n)*DH + d] = f2b(v);
                    }
                } else { // MODE 2
                    int b_ = t / NW, n = t % NW;
                    int head = oc >> 5, d = oc & 31;
                    outp[(((long)b_*NH_ + head)*NW + n)*DH + d] = f2b(v);
                }
            }
        }
    }
}

// ---------------------------------------------------------------------------
// mlp_fused: per 64-token tile x stream: up-proj -> GELU -> down-proj with
// hid held in LDS in A-frag order (never touches HBM). 6 waves, dynamic LDS:
//   AsF  = smem[0 .. 12288)          (4 mtile x 6 kb x 64 lane x 8)
//   hidF = smem[12288 .. 61440+...)  (4 mtile x 24 kb x 64 lane x 8)
// total 122,880 B. Epilogue = MODE-4 resid gather + fp32 store.
// ---------------------------------------------------------------------------
__global__ __launch_bounds__(384)
void mlp_fused(const bf16* __restrict__ xns, const bf16* __restrict__ xnd,
               const short* __restrict__ wfb,
               const float* __restrict__ b1s, const float* __restrict__ b2s,
               const float* __restrict__ b1d, const float* __restrict__ b2d,
               const float* __restrict__ se, const float* __restrict__ de,
               const bf16* __restrict__ pse, const bf16* __restrict__ pde,
               float* __restrict__ dout)
{
    extern __shared__ short smem[];
    short* AsF  = smem;            // ((a*6+kb)*64+lane)*8
    short* hidF = smem + 12288;    // ((m*24+kb)*64+L)*8

    int tid = threadIdx.x;
    int wv = tid >> 6, lane = tid & 63;
    int l15 = lane & 15, g = lane >> 4;
    int strm = blockIdx.y;
    int row0 = blockIdx.x * 64;

    const bf16*  xn  = strm ? xnd : xns;
    const short* wf1 = wfb + (strm ? 589824 : 294912);
    const short* wf2 = wfb + (strm ? 737280 : 442368);
    const float* b1  = strm ? b1d : b1s;
    const float* b2  = strm ? b2d : b2s;
    const float* res = strm ? de  : se;
    const bf16*  prj = strm ? pde : pse;
    float* dst = dout + (strm ? (size_t)TOK*C_DIM : 0);

    // stage xn tile 64x192 frag-ordered (24 slices, 4 per wave)
    #pragma unroll
    for (int p = 0; p < 4; ++p) {
        int pp = wv*4 + p;
        int a = pp / 6, kb = pp % 6;
        gload16(xn + (long)(row0 + 16*a + l15)*C_DIM + 32*kb + 8*g,
                AsF + ((a*6 + kb) << 9));
    }
    __syncthreads();

    // ---- UP: this wave owns hid cols [128*wv, 128*wv+128)
    float bb1[8];
    #pragma unroll
    for (int n = 0; n < 8; ++n) bb1[n] = b1[128*wv + 16*n + l15];

    f32x4 au[4][8];
    #pragma unroll
    for (int m = 0; m < 4; m++)
        #pragma unroll
        for (int n = 0; n < 8; n++)
            au[m][n] = (f32x4){0.f,0.f,0.f,0.f};

    for (int kb = 0; kb < 6; ++kb) {
        short8 af[4];
        #pragma unroll
        for (int m = 0; m < 4; m++) af[m] = *(short8*)(AsF + (((m*6 + kb) << 6) + lane)*8);
        #pragma unroll
        for (int n = 0; n < 8; n++) {
            short8 bfv = *(const short8*)(wf1 + (((long)kb*48 + 8*wv + n)*64 + lane)*8);
            #pragma unroll
            for (int m = 0; m < 4; m++)
                au[m][n] = __builtin_amdgcn_mfma_f32_16x16x32_bf16(af[m], bfv, au[m][n], 0, 0, 0);
        }
    }

    // GELU + scatter into hidF (A-frag order for the down phase)
    #pragma unroll
    for (int m = 0; m < 4; m++) {
        #pragma unroll
        for (int n = 0; n < 8; n++) {
            int hc = 128*wv + 16*n + l15;
            int kb = hc >> 5;
            int Lhi = 16 * ((hc >> 3) & 3);
            int j = hc & 7;
            #pragma unroll
            for (int rr = 0; rr < 4; rr++) {
                float v = au[m][n][rr] + bb1[n];
                float gl = 0.5f * v * (1.0f + erff(v * 0.70710678118654752f));
                int L = (4*g + rr) + Lhi;
                hidF[(((m*24 + kb) << 6) + L)*8 + j] = f2bs(gl);
            }
        }
    }
    __syncthreads();

    // ---- DOWN: this wave owns out cols [32*wv, 32*wv+32)
    f32x4 ad[4][2];
    #pragma unroll
    for (int m = 0; m < 4; m++)
        #pragma unroll
        for (int n = 0; n < 2; n++)
            ad[m][n] = (f32x4){0.f,0.f,0.f,0.f};

    for (int kb = 0; kb < 24; ++kb) {
        short8 af[4];
        #pragma unroll
        for (int m = 0; m < 4; m++) af[m] = *(short8*)(hidF + (((m*24 + kb) << 6) + lane)*8);
        #pragma unroll
        for (int n = 0; n < 2; n++) {
            short8 bfv = *(const short8*)(wf2 + (((long)kb*12 + 2*wv + n)*64 + lane)*8);
            #pragma unroll
            for (int m = 0; m < 4; m++)
                ad[m][n] = __builtin_amdgcn_mfma_f32_16x16x32_bf16(af[m], bfv, ad[m][n], 0, 0, 0);
        }
    }

    // epilogue: residual gather + fp32 store
    #pragma unroll
    for (int m = 0; m < 4; m++) {
        #pragma unroll
        for (int rr = 0; rr < 4; rr++) {
            int tg = row0 + 16*m + 4*g + rr;
            int b = tg / L_TOK, l = tg % L_TOK;
            int h = l / WW2, wcol = l % WW2;
            int hp = h - SS_;    if (hp < 0) hp += HH;
            int wp = wcol - SS_; if (wp < 0) wp += WW2;
            int b_ = b*NWIN + (hp/WS_)*8 + (wp/WS_);
            int n = (hp%WS_)*WS_ + (wp%WS_);
            long wsoff = ((long)b_*NW + n)*C_DIM;
            long goff  = (long)tg*C_DIM;
            #pragma unroll
            for (int n2 = 0; n2 < 2; n2++) {
                int oc = 32*wv + 16*n2 + l15;
                float v = ad[m][n2][rr] + b2[oc];
                dst[goff + oc] = res[goff + oc] + b2f(prj[wsoff + oc]) + v;
            }
        }
    }
}

// ---------------------------------------------------------------------------
// mgemm fallback (fp32 weights from global): 128x64 tile, 4 waves.
// ---------------------------------------------------------------------------
#define BM 128
#define BN 64

template<int MODE>
__global__ __launch_bounds__(256)
void mgemm(const bf16* __restrict__ A1, const bf16* __restrict__ A2, int K1, int K,
           const float* __restrict__ W, const float* __restrict__ bias, int Nn,
           bf16* __restrict__ out, bf16* __restrict__ out2,
           const float* __restrict__ res_src, const bf16* __restrict__ prj,
           int t0, float* __restrict__ dout)
{
    __shared__ short AsF[8][64][8];
    __shared__ short BsF[4][64][8];
    int tid  = threadIdx.x;
    int wid  = tid >> 6, lane = tid & 63;
    int wr   = wid >> 1, wc = wid & 1;
    int row0 = blockIdx.x * BM, col0 = blockIdx.y * BN;

    f32x4 acc[4][2];
    #pragma unroll
    for (int m = 0; m < 4; m++)
        #pragma unroll
        for (int n = 0; n < 2; n++)
            acc[m][n] = (f32x4){0.f, 0.f, 0.f, 0.f};

    int ar = tid >> 2, akseg = tid & 3;
    int bc = tid & 63, bk8 = tid >> 6;

    for (int k0 = 0; k0 < K; k0 += 32) {
        {
            int col = k0 + akseg*8;
            const bf16* asrc = (col < K1) ? A1 : A2;
            int akc = (col < K1) ? col : col - K1;
            #pragma unroll
            for (int rr = 0; rr < 2; rr++) {
                int r = ar + rr*64;
                short8 av = *(const short8*)(asrc + (long)(row0 + r)*K1 + akc);
                *((short8*)&AsF[r >> 4][(r & 15) + (akseg << 4)][0]) = av;
            }
        }
        {
            short8 bv;
            #pragma unroll
            for (int j = 0; j < 8; j++)
                bv[j] = f2bs(W[(long)(k0 + bk8*8 + j)*Nn + col0 + bc]);
            *((short8*)&BsF[bc >> 4][(bc & 15) + (bk8 << 4)][0]) = bv;
        }
        __syncthreads();
        short8 af[4], bfr[2];
        #pragma unroll
        for (int m = 0; m < 4; m++) af[m]  = *((short8*)&AsF[wr*4 + m][lane][0]);
        #pragma unroll
        for (int n = 0; n < 2; n++) bfr[n] = *((short8*)&BsF[wc*2 + n][lane][0]);
        #pragma unroll
        for (int m = 0; m < 4; m++)
            #pragma unroll
            for (int n = 0; n < 2; n++)
                acc[m][n] = __builtin_amdgcn_mfma_f32_16x16x32_bf16(af[m], bfr[n], acc[m][n], 0, 0, 0);
        __syncthreads();
    }

    #pragma unroll
    for (int m = 0; m < 4; m++) {
        #pragma unroll
        for (int rr = 0; rr < 4; rr++) {
            int t = row0 + wr*64 + m*16 + (lane >> 4)*4 + rr;
            if (MODE == 4) {
                int tg = t0 + t;
                int b = tg / L_TOK, l = tg % L_TOK;
                int h = l / WW2, wcol = l % WW2;
                int hp = h - SS_;    if (hp < 0) hp += HH;
                int wp = wcol - SS_; if (wp < 0) wp += WW2;
                int b_ = b*NWIN + (hp/WS_)*8 + (wp/WS_);
                int n  = (hp%WS_)*WS_ + (wp%WS_);
                long wsoff = ((long)b_*NW + n)*C_DIM;
                long goff  = (long)tg*C_DIM;
                #pragma unroll
                for (int n2 = 0; n2 < 2; n2++) {
                    int oc = col0 + wc*32 + n2*16 + (lane & 15);
                    float v = acc[m][n2][rr] + bias[oc];
                    dout[goff + oc] = res_src[goff + oc] + b2f(prj[wsoff + oc]) + v;
                }
            } else {
                #pragma unroll
                for (int n2 = 0; n2 < 2; n2++) {
                    int oc = col0 + wc*32 + n2*16 + (lane & 15);
                    float v = acc[m][n2][rr] + bias[oc];
                    if (MODE == 0) {
                        out[(long)t*Nn + oc] = f2b(v);
                    } else if (MODE == 1) {
                        int b_ = t / NW, n = t % NW;
                        if (oc < C_DIM) {
                            int head = oc >> 5, d = oc & 31;
                            out[(((long)b_*NH_ + head)*NW + n)*DH + d] = f2b(v * 0.17677669529663687f);
                        } else {
                            int och = oc - C_DIM;
                            int head = och >> 5, d = och & 31;
                            out2[(((long)b_*NH_ + head)*NW + n)*DH + d] = f2b(v);
                        }
                    } else if (MODE == 2) {
                        int b_ = t / NW, n = t % NW;
                        int head = oc >> 5, d = oc & 31;
                        out[(((long)b_*NH_ + head)*NW + n)*DH + d] = f2b(v);
                    } else {
                        float g2 = 0.5f * v * (1.0f + erff(v * 0.70710678118654752f));
                        out[(long)t*Nn + oc] = f2b(g2);
                    }
                }
            }
        }
    }
}

// ---------------------------------------------------------------------------
// MFMA attention: 1 wave per (window,head), 2 waves/block. (unchanged)
// ---------------------------------------------------------------------------
#define PSTR 72
#define VSTR 72

__global__ __launch_bounds__(128)
void attn_mfma(const bf16* __restrict__ qb, const bf16* __restrict__ kb,
               const bf16* __restrict__ vse, const bf16* __restrict__ vde,
               const float* __restrict__ rpb,
               bf16* __restrict__ ose, bf16* __restrict__ ode)
{
    __shared__ float rpbs[169*NH_];
    __shared__ short P[2][64][PSTR];
    __shared__ short VTs[2][32][VSTR];
    __shared__ short VTd[2][32][VSTR];
    int tid = threadIdx.x, wid = tid >> 6, lane = tid & 63;
    for (int i = tid; i < 169*NH_; i += 128) rpbs[i] = rpb[i];
    __syncthreads();

    int bh = blockIdx.x*2 + wid;
    int b_ = bh / NH_, head = bh % NH_;
    int w = b_ & (NWIN-1);
    int wh = w >> 3, ww = w & 7;
    long base = (long)bh * (NW*DH);
    int l15 = lane & 15, g = lane >> 4;

    short8 qf[4], kf[4];
    #pragma unroll
    for (int mi = 0; mi < 4; mi++) {
        int r = l15 + 16*mi; if (r > 48) r = 48;
        qf[mi] = *(const short8*)(qb + base + r*DH + 8*g);
    }
    #pragma unroll
    for (int ni = 0; ni < 4; ni++) {
        int r = l15 + 16*ni; if (r > 48) r = 48;
        kf[ni] = *(const short8*)(kb + base + r*DH + 8*g);
    }

    f32x4 sA[4][4];
    #pragma unroll
    for (int mi = 0; mi < 4; mi++)
        #pragma unroll
        for (int ni = 0; ni < 4; ni++)
            sA[mi][ni] = (f32x4){0.f,0.f,0.f,0.f};
    #pragma unroll
    for (int mi = 0; mi < 4; mi++)
        #pragma unroll
        for (int ni = 0; ni < 4; ni++)
            sA[mi][ni] = __builtin_amdgcn_mfma_f32_16x16x32_bf16(qf[mi], kf[ni], sA[mi][ni], 0, 0, 0);

    {
        int j0 = lane >> 2, seg = lane & 3;
        #pragma unroll
        for (int it = 0; it < 4; ++it) {
            int j = j0 + 16*it;
            short8 a = {0,0,0,0,0,0,0,0}, bv = {0,0,0,0,0,0,0,0};
            if (j < NW) {
                a  = *(const short8*)(vse + base + j*DH + seg*8);
                bv = *(const short8*)(vde + base + j*DH + seg*8);
            }
            #pragma unroll
            for (int s2 = 0; s2 < 8; ++s2) {
                VTs[wid][seg*8 + s2][j] = a[s2];
                VTd[wid][seg*8 + s2][j] = bv[s2];
            }
        }
    }

    int jv[4], j7r_[4], j7c_[4], jrh_[4], jrc_[4];
    #pragma unroll
    for (int ni = 0; ni < 4; ++ni) {
        int j = 16*ni + l15;
        jv[ni] = (j < NW);
        int a = (j*37) >> 8; int c = j - 7*a;
        j7r_[ni] = a; j7c_[ni] = c;
        int jh = wh*7 + a, jw = ww*7 + c;
        jrh_[ni] = (jh >= 49) + (jh >= 53);
        jrc_[ni] = (jw >= 49) + (jw >= 53);
    }

    #pragma unroll
    for (int mi = 0; mi < 4; mi++) {
        #pragma unroll
        for (int rr = 0; rr < 4; rr++) {
            int i = 16*mi + 4*g + rr;
            int iv = (i < NW);
            int i7r = (i*37) >> 8; int i7c = i - 7*i7r;
            int ih = wh*7 + i7r, iw = ww*7 + i7c;
            int irh = (ih >= 49) + (ih >= 53), irc = (iw >= 49) + (iw >= 53);
            float sv[4];
            #pragma unroll
            for (int ni = 0; ni < 4; ni++) {
                if (iv && jv[ni]) {
                    int ri = (i7r - j7r_[ni] + 6)*13 + (i7c - j7c_[ni] + 6);
                    float msk = (irh == jrh_[ni] && irc == jrc_[ni]) ? 0.f : -100.f;
                    sv[ni] = sA[mi][ni][rr] + rpbs[ri*NH_ + head] + msk;
                } else {
                    sv[ni] = -1e30f;
                }
            }
            float mx = fmaxf(fmaxf(sv[0], sv[1]), fmaxf(sv[2], sv[3]));
            mx = fmaxf(mx, __shfl_xor(mx, 1));
            mx = fmaxf(mx, __shfl_xor(mx, 2));
            mx = fmaxf(mx, __shfl_xor(mx, 4));
            mx = fmaxf(mx, __shfl_xor(mx, 8));
            float e[4], sum = 0.f;
            #pragma unroll
            for (int ni = 0; ni < 4; ni++) { e[ni] = __expf(sv[ni] - mx); sum += e[ni]; }
            sum += __shfl_xor(sum, 1);
            sum += __shfl_xor(sum, 2);
            sum += __shfl_xor(sum, 4);
            sum += __shfl_xor(sum, 8);
            float inv = 1.0f / sum;
            #pragma unroll
            for (int ni = 0; ni < 4; ni++)
                P[wid][i][16*ni + l15] = f2bs(e[ni] * inv);
        }
    }
    __syncthreads();

    f32x4 o1[4][2], o2[4][2];
    #pragma unroll
    for (int mi = 0; mi < 4; mi++)
        #pragma unroll
        for (int di = 0; di < 2; di++) {
            o1[mi][di] = (f32x4){0.f,0.f,0.f,0.f};
            o2[mi][di] = (f32x4){0.f,0.f,0.f,0.f};
        }
    #pragma unroll
    for (int mi = 0; mi < 4; mi++) {
        #pragma unroll
        for (int kk = 0; kk < 2; kk++) {
            short8 ap = *((short8*)&P[wid][16*mi + l15][kk*32 + 8*g]);
            #pragma unroll
            for (int di = 0; di < 2; di++) {
                short8 bv1 = *((short8*)&VTs[wid][16*di + l15][kk*32 + 8*g]);
                o1[mi][di] = __builtin_amdgcn_mfma_f32_16x16x32_bf16(ap, bv1, o1[mi][di], 0, 0, 0);
                short8 bv2 = *((short8*)&VTd[wid][16*di + l15][kk*32 + 8*g]);
                o2[mi][di] = __builtin_amdgcn_mfma_f32_16x16x32_bf16(ap, bv2, o2[mi][di], 0, 0, 0);
            }
        }
    }

    #pragma unroll
    for (int mi = 0; mi < 4; mi++) {
        #pragma unroll
        for (int rr = 0; rr < 4; rr++) {
            int i = 16*mi + 4*g + rr;
            if (i < NW) {
                long ob = ((long)b_*NW + i)*C_DIM + head*DH;
                #pragma unroll
                for (int di = 0; di < 2; di++) {
                    ose[ob + 16*di + l15] = f2b(o1[mi][di][rr]);
                    ode[ob + 16*di + l15] = f2b(o2[mi][di][rr]);
                }
            }
        }
    }
}

// ---------------------------------------------------------------------------
// Fused window-reverse + un-shift + residual + LN2 (xn only).
// ---------------------------------------------------------------------------
__global__ void resid_ln2_kernel(const float* __restrict__ se, const float* __restrict__ de,
                                 const bf16* __restrict__ pse, const bf16* __restrict__ pde,
                                 const float* __restrict__ g2s, const float* __restrict__ bb2s,
                                 const float* __restrict__ g2d, const float* __restrict__ bb2d,
                                 bf16* __restrict__ xns, bf16* __restrict__ xnd)
{
    int t = blockIdx.x, tid = threadIdx.x;
    int b = t / L_TOK, l = t % L_TOK;
    int h = l / WW2, wc = l % WW2;
    int hp = h - SS_;  if (hp < 0) hp += HH;
    int wp = wc - SS_; if (wp < 0) wp += WW2;
    int b_ = b*NWIN + (hp/WS_)*8 + (wp/WS_);
    int n  = (hp%WS_)*WS_ + (wp%WS_);
    long wsoff = ((long)b_*NW + n)*C_DIM;
    long off   = (long)t*C_DIM;
    {
        float x0 = se[off+tid]     + b2f(pse[wsoff+tid]);
        float x1 = se[off+tid+64]  + b2f(pse[wsoff+tid+64]);
        float x2 = se[off+tid+128] + b2f(pse[wsoff+tid+128]);
        float s  = wave_sum64(x0+x1+x2);
        float ss = wave_sum64(x0*x0 + x1*x1 + x2*x2);
        float mean = s * (1.0f/192.0f);
        float var  = ss * (1.0f/192.0f) - mean*mean;
        float rstd = rsqrtf(var + 1e-5f);
        xns[off+tid]     = f2b((x0-mean)*rstd*g2s[tid]     + bb2s[tid]);
        xns[off+tid+64]  = f2b((x1-mean)*rstd*g2s[tid+64]  + bb2s[tid+64]);
        xns[off+tid+128] = f2b((x2-mean)*rstd*g2s[tid+128] + bb2s[tid+128]);
    }
    {
        float x0 = de[off+tid]     + b2f(pde[wsoff+tid]);
        float x1 = de[off+tid+64]  + b2f(pde[wsoff+tid+64]);
        float x2 = de[off+tid+128] + b2f(pde[wsoff+tid+128]);
        float s  = wave_sum64(x0+x1+x2);
        float ss = wave_sum64(x0*x0 + x1*x1 + x2*x2);
        float mean = s * (1.0f/192.0f);
        float var  = ss * (1.0f/192.0f) - mean*mean;
        float rstd = rsqrtf(var + 1e-5f);
        xnd[off+tid]     = f2b((x0-mean)*rstd*g2d[tid]     + bb2d[tid]);
        xnd[off+tid+64]  = f2b((x1-mean)*rstd*g2d[tid+64]  + bb2d[tid+64]);
        xnd[off+tid+128] = f2b((x2-mean)*rstd*g2d[tid+128] + bb2d[tid+128]);
    }
}

// ---------------------------------------------------------------------------
extern "C" void kernel_launch(void* const* d_in, const int* in_sizes, int n_in,
                              void* d_out, int out_size, void* d_ws, size_t ws_size,
                              hipStream_t stream)
{
    const float* se     = (const float*)d_in[0];
    const float* de     = (const float*)d_in[1];
    const float* co     = (const float*)d_in[2];
    const float* n1se_g = (const float*)d_in[4];
    const float* n1se_b = (const float*)d_in[5];
    const float* n1de_g = (const float*)d_in[6];
    const float* n1de_b = (const float*)d_in[7];
    const float* rpb    = (const float*)d_in[8];
    const float* vse_w  = (const float*)d_in[9];
    const float* vse_b  = (const float*)d_in[10];
    const float* vde_w  = (const float*)d_in[11];
    const float* vde_b  = (const float*)d_in[12];
    const float* qk_w   = (const float*)d_in[13];
    const float* qk_b   = (const float*)d_in[14];
    const float* pse_w  = (const float*)d_in[15];
    const float* pse_b  = (const float*)d_in[16];
    const float* pde_w  = (const float*)d_in[17];
    const float* pde_b  = (const float*)d_in[18];
    const float* n2se_g = (const float*)d_in[19];
    const float* n2se_b = (const float*)d_in[20];
    const float* n2de_g = (const float*)d_in[21];
    const float* n2de_b = (const float*)d_in[22];
    const float* mse_w1 = (const float*)d_in[23];
    const float* mse_b1 = (const float*)d_in[24];
    const float* mse_w2 = (const float*)d_in[25];
    const float* mse_b2 = (const float*)d_in[26];
    const float* mde_w1 = (const float*)d_in[27];
    const float* mde_b1 = (const float*)d_in[28];
    const float* mde_w2 = (const float*)d_in[29];
    const float* mde_b2 = (const float*)d_in[30];

    char* ws = (char*)d_ws;
    const size_t U = (size_t)TOK * C_DIM * 2;   // 19,267,584 bytes
    bf16* sw  = (bf16*)(ws + 0*U);
    bf16* dw  = (bf16*)(ws + 1*U);
    bf16* cw  = (bf16*)(ws + 2*U);
    bf16* vse = (bf16*)(ws + 3*U);
    bf16* vde = (bf16*)(ws + 4*U);
    bf16* ode = (bf16*)(ws + 5*U);
    bf16* qb  = (bf16*)(ws + 0*U);
    bf16* kb  = (bf16*)(ws + 1*U);
    bf16* ose = (bf16*)(ws + 2*U);
    bf16* pse = (bf16*)(ws + 0*U);
    bf16* pde = (bf16*)(ws + 1*U);
    bf16* xns = (bf16*)(ws + 2*U);
    bf16* xnd = (bf16*)(ws + 3*U);
    bf16* hid = (bf16*)(ws + 4*U);
    short* wfb = (short*)(ws + 6*U);            // 884,736 bf16 = 1.73 MB

    const bool frag = (ws_size >= 6*U + 884736ull*2ull);
    float* dout = (float*)d_out;
    const int CH = TOK/2;
    const int NX = TOK/128;   // 392

    if (frag)
        wconv<<<dim3(72, 9), 256, 0, stream>>>(vse_w, vde_w, qk_w, pse_w, pde_w,
                                               mse_w1, mse_w2, mde_w1, mde_w2, wfb);
    prep_kernel<<<TOK, 64, 0, stream>>>(se, de, co, n1se_g, n1se_b, n1de_g, n1de_b, sw, dw, cw);

    if (frag) {
        // V merged (both streams), K=384
        fgemm2<2,true><<<dim3(NX*2, 1), 384, 0, stream>>>(sw, cw, C_DIM, 2*C_DIM, wfb + 0, vse_b, C_DIM,
                                                          vse, nullptr,
                                                          dw, cw, wfb + 73728, vde_b, vde, NX);
        // QK
        fgemm2<1,false><<<dim3(NX, 2), 384, 0, stream>>>(cw, cw, C_DIM, C_DIM, wfb + 147456, qk_b, 384,
                                                         qb, kb,
                                                         nullptr, nullptr, nullptr, nullptr, nullptr, 0);
    } else {
        mgemm<2><<<dim3(TOK/BM, C_DIM/BN), 256, 0, stream>>>(sw, cw, C_DIM, 2*C_DIM, vse_w, vse_b, C_DIM,
                                                             vse, nullptr, nullptr, nullptr, 0, nullptr);
        mgemm<2><<<dim3(TOK/BM, C_DIM/BN), 256, 0, stream>>>(dw, cw, C_DIM, 2*C_DIM, vde_w, vde_b, C_DIM,
                                                             vde, nullptr, nullptr, nullptr, 0, nullptr);
        mgemm<1><<<dim3(TOK/BM, 384/BN), 256, 0, stream>>>(cw, cw, C_DIM, C_DIM, qk_w, qk_b, 384,
                                                           qb, kb, nullptr, nullptr, 0, nullptr);
    }

    attn_mfma<<<BWIN*NH_/2, 128, 0, stream>>>(qb, kb, vse, vde, rpb, ose, ode);

    if (frag) {
        // P merged (both streams)
        fgemm2<0,true><<<dim3(NX*2, 1), 384, 0, stream>>>(ose, ose, C_DIM, C_DIM, wfb + 221184, pse_b, C_DIM,
                                                          pse, nullptr,
                                                          ode, ode, wfb + 258048, pde_b, pde, NX);
    } else {
        mgemm<0><<<dim3(TOK/BM, C_DIM/BN), 256, 0, stream>>>(ose, ose, C_DIM, C_DIM, pse_w, pse_b, C_DIM,
                                                             pse, nullptr, nullptr, nullptr, 0, nullptr);
        mgemm<0><<<dim3(TOK/BM, C_DIM/BN), 256, 0, stream>>>(ode, ode, C_DIM, C_DIM, pde_w, pde_b, C_DIM,
                                                             pde, nullptr, nullptr, nullptr, 0, nullptr);
    }

    resid_ln2_kernel<<<TOK, 64, 0, stream>>>(se, de, pse, pde,
                                             n2se_g, n2se_b, n2de_g, n2de_b, xns, xnd);

    if (frag) {
        // fused MLP: both streams, hid lives in LDS (122,880 B dynamic)
        mlp_fused<<<dim3(TOK/64, 2), 384, 122880, stream>>>(xns, xnd, wfb,
                                                            mse_b1, mse_b2, mde_b1, mde_b2,
                                                            se, de, pse, pde, dout);
    } else {
        for (int c0 = 0; c0 < 2; c0++) {
            int t0 = c0 * CH;
            mgemm<3><<<dim3(CH/BM, HID_/BN), 256, 0, stream>>>(xns + (long)t0*C_DIM, xns + (long)t0*C_DIM,
                                                               C_DIM, C_DIM, mse_w1, mse_b1, HID_,
                                                               hid, nullptr, nullptr, nullptr, 0, nullptr);
            mgemm<4><<<dim3(CH/BM, C_DIM/BN), 256, 0, stream>>>(hid, hid, HID_, HID_, mse_w2, mse_b2, C_DIM,
                                                                nullptr, nullptr, se, pse, t0, dout);
        }
        for (int c0 = 0; c0 < 2; c0++) {
            int t0 = c0 * CH;
            mgemm<3><<<dim3(CH/BM, HID_/BN), 256, 0, stream>>>(xnd + (long)t0*C_DIM, xnd + (long)t0*C_DIM,
                                                               C_DIM, C_DIM, mde_w1, mde_b1, HID_,
                                                               hid, nullptr, nullptr, nullptr, 0, nullptr);
            mgemm<4><<<dim3(CH/BM, C_DIM/BN), 256, 0, stream>>>(hid, hid, HID_, HID_, mde_w2, mde_b2, C_DIM,
                                                                nullptr, nullptr, de, pde, t0,
                                                                dout + (size_t)TOK*C_DIM);
        }
    }
}

// Round 9
// 441.643 us; speedup vs baseline: 1.0275x; 1.0049x over previous
//
#include <hip/hip_runtime.h>
#include <hip/hip_bf16.h>
#include <math.h>
#include <stdint.h>

typedef __hip_bfloat16 bf16;
typedef __attribute__((ext_vector_type(8))) short short8;
typedef __attribute__((ext_vector_type(4))) float f32x4;

#define B_SZ   16
#define HH     56
#define WW2    56
#define L_TOK  3136
#define C_DIM  192
#define NH_    6
#define DH     32
#define WS_    7
#define SS_    3
#define NW     49
#define NWIN   64
#define BWIN   (B_SZ*NWIN)  // 1024
#define TOK    (BWIN*NW)    // 50176
#define HID_   768

__device__ __forceinline__ float b2f(bf16 x){ return __bfloat162float(x); }
__device__ __forceinline__ bf16  f2b(float x){ return __float2bfloat16(x); }
__device__ __forceinline__ short f2bs(float x){ bf16 h = __float2bfloat16(x); return *reinterpret_cast<short*>(&h); }

// async global->LDS, 16B per lane; LDS dest = wave-uniform base + lane*16
__device__ __forceinline__ void gload16(const void* g, void* l) {
    __builtin_amdgcn_global_load_lds(
        (const __attribute__((address_space(1))) void*)(uintptr_t)g,
        (__attribute__((address_space(3))) void*)(uintptr_t)l, 16, 0, 0);
}

__device__ __forceinline__ float wave_sum64(float v){
    #pragma unroll
    for (int off = 32; off > 0; off >>= 1) v += __shfl_xor(v, off, 64);
    return v;
}

// ---------------------------------------------------------------------------
// LN1(se), LN1(de), copy(co) + cyclic shift + window partition.
// ---------------------------------------------------------------------------
__global__ void prep_kernel(const float* __restrict__ se, const float* __restrict__ de,
                            const float* __restrict__ co,
                            const float* __restrict__ g1s, const float* __restrict__ b1s,
                            const float* __restrict__ g1d, const float* __restrict__ b1d,
                            bf16* __restrict__ sw, bf16* __restrict__ dw, bf16* __restrict__ cw)
{
    int t   = blockIdx.x;
    int tid = threadIdx.x;
    int b_  = t / NW, n = t % NW;
    int b   = b_ / NWIN, w = b_ % NWIN;
    int wh  = w >> 3, wwi = w & 7;
    int i   = n / WS_, j = n % WS_;
    int hs  = wh*WS_ + i, ws = wwi*WS_ + j;
    int hsrc = hs + SS_; if (hsrc >= HH)  hsrc -= HH;
    int wsrc = ws + SS_; if (wsrc >= WW2) wsrc -= WW2;
    long src = ((long)(b*L_TOK + hsrc*WW2 + wsrc)) * C_DIM;
    long dst = (long)t * C_DIM;

    {
        float x0 = se[src+tid], x1 = se[src+tid+64], x2 = se[src+tid+128];
        float s  = wave_sum64(x0+x1+x2);
        float ss = wave_sum64(x0*x0 + x1*x1 + x2*x2);
        float mean = s * (1.0f/192.0f);
        float var  = ss * (1.0f/192.0f) - mean*mean;
        float rstd = rsqrtf(var + 1e-5f);
        sw[dst+tid]     = f2b((x0-mean)*rstd*g1s[tid]     + b1s[tid]);
        sw[dst+tid+64]  = f2b((x1-mean)*rstd*g1s[tid+64]  + b1s[tid+64]);
        sw[dst+tid+128] = f2b((x2-mean)*rstd*g1s[tid+128] + b1s[tid+128]);
    }
    {
        float x0 = de[src+tid], x1 = de[src+tid+64], x2 = de[src+tid+128];
        float s  = wave_sum64(x0+x1+x2);
        float ss = wave_sum64(x0*x0 + x1*x1 + x2*x2);
        float mean = s * (1.0f/192.0f);
        float var  = ss * (1.0f/192.0f) - mean*mean;
        float rstd = rsqrtf(var + 1e-5f);
        dw[dst+tid]     = f2b((x0-mean)*rstd*g1d[tid]     + b1d[tid]);
        dw[dst+tid+64]  = f2b((x1-mean)*rstd*g1d[tid+64]  + b1d[tid+64]);
        dw[dst+tid+128] = f2b((x2-mean)*rstd*g1d[tid+128] + b1d[tid+128]);
    }
    cw[dst+tid]     = f2b(co[src+tid]);
    cw[dst+tid+64]  = f2b(co[src+tid+64]);
    cw[dst+tid+128] = f2b(co[src+tid+128]);
}

// ---------------------------------------------------------------------------
// Weight pre-convert: fp32 [K][N] -> bf16 MFMA-B-fragment order.
// ---------------------------------------------------------------------------
__global__ __launch_bounds__(256)
void wconv(const float* w0,const float* w1,const float* w2,const float* w3,const float* w4,
           const float* w5,const float* w6,const float* w7,const float* w8, short* dst)
{
    const float* src; int K, N; long doff;
    switch (blockIdx.y) {
      case 0: src=w0; K=384; N=192; doff=0;      break;
      case 1: src=w1; K=384; N=192; doff=73728;  break;
      case 2: src=w2; K=192; N=384; doff=147456; break;
      case 3: src=w3; K=192; N=192; doff=221184; break;
      case 4: src=w4; K=192; N=192; doff=258048; break;
      case 5: src=w5; K=192; N=768; doff=294912; break;
      case 6: src=w6; K=768; N=192; doff=442368; break;
      case 7: src=w7; K=192; N=768; doff=589824; break;
      default:src=w8; K=768; N=192; doff=737280; break;
    }
    int nblk = (K>>5)*(N>>6);
    int bid = blockIdx.x;
    if (bid >= nblk) return;
    int kb = bid / (N>>6), nb = bid % (N>>6);
    __shared__ float tile[32][65];
    int tid = threadIdx.x;
    #pragma unroll
    for (int it = 0; it < 8; ++it) {
        int idx = tid + it*256;
        int r = idx >> 6, c = idx & 63;
        tile[r][c] = src[(long)(kb*32 + r)*N + nb*64 + c];
    }
    __syncthreads();
    int lane = tid & 63, nl = tid >> 6;
    short8 v;
    #pragma unroll
    for (int j = 0; j < 8; ++j)
        v[j] = f2bs(tile[(lane>>4)*8 + j][nl*16 + (lane&15)]);
    long nig = (long)nb*4 + nl;
    *(short8*)(dst + doff + (((long)kb*(N>>4) + nig)*64 + lane)*8) = v;
}

// ---------------------------------------------------------------------------
// fgemm2: C = A(bf16) @ Wfrag(bf16) + bias. MR16 16-row slices per tile
// (8 -> 128-row tile, 4 -> 64-row), 6 waves (2x3 or on 64-row: 2x3 of 32x64),
// dbuf LDS via global_load_lds. DUAL: blockIdx.x >= nxblk -> second stream.
// MODE 0 plain / 1 qk-scatter / 2 v-scatter / 3 GELU / 4 resid->fp32 dout.
// ---------------------------------------------------------------------------
template<int MODE, bool DUAL, int MR16>
__global__ __launch_bounds__(384)
void fgemm2(const bf16* __restrict__ A1, const bf16* __restrict__ A2, int K1, int K,
            const short* __restrict__ wf, const float* __restrict__ bias, int Nn,
            bf16* __restrict__ out, bf16* __restrict__ out2,
            const bf16* __restrict__ A1b, const bf16* __restrict__ A2b,
            const short* __restrict__ wfB, const float* __restrict__ biasB,
            bf16* __restrict__ outB,
            const float* __restrict__ res, const bf16* __restrict__ prj,
            float* __restrict__ dout4,
            const float* __restrict__ resB, const bf16* __restrict__ prjB,
            float* __restrict__ dout4B,
            int t0, int nxblk)
{
    __shared__ short AsF[2][MR16][64][8];
    const int MROWS = MR16 * 16;
    const int MPW   = MR16 / 2;
    int tid = threadIdx.x;
    int wid = tid >> 6, lane = tid & 63;
    int wr = (wid >= 3) ? 1 : 0, wc = wid - wr*3;
    int l15 = lane & 15, g = lane >> 4;

    int bx = blockIdx.x;
    const bf16 *A1p = A1, *A2p = A2; const short* wfp = wf;
    const float* biasp = bias; bf16* outp = out;
    const float* resp = res; const bf16* prjp = prj; float* doutp = dout4;
    if (DUAL && bx >= nxblk) {
        bx -= nxblk; A1p = A1b; A2p = A2b; wfp = wfB; biasp = biasB; outp = outB;
        resp = resB; prjp = prjB; doutp = dout4B;
    }
    int row0 = bx * MROWS, col0 = blockIdx.y * 192;
    const int ntiles = Nn >> 4;

    f32x4 acc[MPW][4];
    #pragma unroll
    for (int m = 0; m < MPW; m++)
        #pragma unroll
        for (int n = 0; n < 4; n++)
            acc[m][n] = (f32x4){0.f,0.f,0.f,0.f};

    int nk = K >> 5;
    #define STAGE(buf_, k0_) {                                                   \
        int colk = (k0_) + (g << 3);                                             \
        const bf16* asrc = (colk < K1) ? A1p : A2p;                              \
        int kc = (colk < K1) ? colk : colk - K1;                                 \
        if (wid < MR16)                                                          \
            gload16(asrc + (long)(row0 + wid*16 + l15)*K1 + kc,                  \
                    &AsF[buf_][wid][0][0]);                                      \
        if (MR16 == 8 && wid < 2)                                                \
            gload16(asrc + (long)(row0 + (6+wid)*16 + l15)*K1 + kc,              \
                    &AsF[buf_][(MR16==8 ? 6+wid : 0)][0][0]);                    \
    }

    STAGE(0, 0);
    __syncthreads();
    for (int t = 0; t < nk; ++t) {
        int buf = t & 1;
        if (t + 1 < nk) STAGE(buf ^ 1, (t+1) << 5);
        short8 af[MPW], bf4[4];
        #pragma unroll
        for (int m = 0; m < MPW; m++) af[m] = *((short8*)&AsF[buf][wr*MPW + m][lane][0]);
        const short* wbase = wfp + (((long)t*ntiles + (col0>>4) + wc*4)*64 + lane)*8;
        #pragma unroll
        for (int n = 0; n < 4; n++) bf4[n] = *(const short8*)(wbase + n*512);
        #pragma unroll
        for (int m = 0; m < MPW; m++)
            #pragma unroll
            for (int n = 0; n < 4; n++)
                acc[m][n] = __builtin_amdgcn_mfma_f32_16x16x32_bf16(af[m], bf4[n], acc[m][n], 0, 0, 0);
        __syncthreads();
    }
    #undef STAGE

    #pragma unroll
    for (int m = 0; m < MPW; m++) {
        #pragma unroll
        for (int rr = 0; rr < 4; rr++) {
            int t = row0 + wr*(MROWS/2) + m*16 + g*4 + rr;
            if (MODE == 4) {
                int tg = t0 + t;
                int b = tg / L_TOK, l = tg % L_TOK;
                int h = l / WW2, wcol = l % WW2;
                int hp = h - SS_;    if (hp < 0) hp += HH;
                int wp = wcol - SS_; if (wp < 0) wp += WW2;
                int b_ = b*NWIN + (hp/WS_)*8 + (wp/WS_);
                int n = (hp%WS_)*WS_ + (wp%WS_);
                long wsoff = ((long)b_*NW + n)*C_DIM;
                long goff  = (long)tg*C_DIM;
                #pragma unroll
                for (int n2 = 0; n2 < 4; n2++) {
                    int oc = col0 + wc*64 + n2*16 + l15;
                    float v = acc[m][n2][rr] + biasp[oc];
                    doutp[goff + oc] = resp[goff + oc] + b2f(prjp[wsoff + oc]) + v;
                }
            } else {
                #pragma unroll
                for (int n2 = 0; n2 < 4; n2++) {
                    int oc = col0 + wc*64 + n2*16 + l15;
                    float v = acc[m][n2][rr] + biasp[oc];
                    if (MODE == 0) {
                        outp[(long)t*Nn + oc] = f2b(v);
                    } else if (MODE == 1) {
                        int b_ = t / NW, n = t % NW;
                        if (oc < C_DIM) {
                            int head = oc >> 5, d = oc & 31;
                            outp[(((long)b_*NH_ + head)*NW + n)*DH + d] = f2b(v * 0.17677669529663687f);
                        } else {
                            int och = oc - C_DIM;
                            int head = och >> 5, d = och & 31;
                            out2[(((long)b_*NH_ + head)*NW + n)*DH + d] = f2b(v);
                        }
                    } else if (MODE == 2) {
                        int b_ = t / NW, n = t % NW;
                        int head = oc >> 5, d = oc & 31;
                        outp[(((long)b_*NH_ + head)*NW + n)*DH + d] = f2b(v);
                    } else { // MODE 3
                        float g2 = 0.5f * v * (1.0f + erff(v * 0.70710678118654752f));
                        outp[(long)t*Nn + oc] = f2b(g2);
                    }
                }
            }
        }
    }
}

// ---------------------------------------------------------------------------
// mgemm fallback (fp32 weights from global): 128x64 tile, 4 waves.
// ---------------------------------------------------------------------------
#define BM 128
#define BN 64

template<int MODE>
__global__ __launch_bounds__(256)
void mgemm(const bf16* __restrict__ A1, const bf16* __restrict__ A2, int K1, int K,
           const float* __restrict__ W, const float* __restrict__ bias, int Nn,
           bf16* __restrict__ out, bf16* __restrict__ out2,
           const float* __restrict__ res_src, const bf16* __restrict__ prj,
           int t0, float* __restrict__ dout)
{
    __shared__ short AsF[8][64][8];
    __shared__ short BsF[4][64][8];
    int tid  = threadIdx.x;
    int wid  = tid >> 6, lane = tid & 63;
    int wr   = wid >> 1, wc = wid & 1;
    int row0 = blockIdx.x * BM, col0 = blockIdx.y * BN;

    f32x4 acc[4][2];
    #pragma unroll
    for (int m = 0; m < 4; m++)
        #pragma unroll
        for (int n = 0; n < 2; n++)
            acc[m][n] = (f32x4){0.f, 0.f, 0.f, 0.f};

    int ar = tid >> 2, akseg = tid & 3;
    int bc = tid & 63, bk8 = tid >> 6;

    for (int k0 = 0; k0 < K; k0 += 32) {
        {
            int col = k0 + akseg*8;
            const bf16* asrc = (col < K1) ? A1 : A2;
            int akc = (col < K1) ? col : col - K1;
            #pragma unroll
            for (int rr = 0; rr < 2; rr++) {
                int r = ar + rr*64;
                short8 av = *(const short8*)(asrc + (long)(row0 + r)*K1 + akc);
                *((short8*)&AsF[r >> 4][(r & 15) + (akseg << 4)][0]) = av;
            }
        }
        {
            short8 bv;
            #pragma unroll
            for (int j = 0; j < 8; j++)
                bv[j] = f2bs(W[(long)(k0 + bk8*8 + j)*Nn + col0 + bc]);
            *((short8*)&BsF[bc >> 4][(bc & 15) + (bk8 << 4)][0]) = bv;
        }
        __syncthreads();
        short8 af[4], bfr[2];
        #pragma unroll
        for (int m = 0; m < 4; m++) af[m]  = *((short8*)&AsF[wr*4 + m][lane][0]);
        #pragma unroll
        for (int n = 0; n < 2; n++) bfr[n] = *((short8*)&BsF[wc*2 + n][lane][0]);
        #pragma unroll
        for (int m = 0; m < 4; m++)
            #pragma unroll
            for (int n = 0; n < 2; n++)
                acc[m][n] = __builtin_amdgcn_mfma_f32_16x16x32_bf16(af[m], bfr[n], acc[m][n], 0, 0, 0);
        __syncthreads();
    }

    #pragma unroll
    for (int m = 0; m < 4; m++) {
        #pragma unroll
        for (int rr = 0; rr < 4; rr++) {
            int t = row0 + wr*64 + m*16 + (lane >> 4)*4 + rr;
            if (MODE == 4) {
                int tg = t0 + t;
                int b = tg / L_TOK, l = tg % L_TOK;
                int h = l / WW2, wcol = l % WW2;
                int hp = h - SS_;    if (hp < 0) hp += HH;
                int wp = wcol - SS_; if (wp < 0) wp += WW2;
                int b_ = b*NWIN + (hp/WS_)*8 + (wp/WS_);
                int n  = (hp%WS_)*WS_ + (wp%WS_);
                long wsoff = ((long)b_*NW + n)*C_DIM;
                long goff  = (long)tg*C_DIM;
                #pragma unroll
                for (int n2 = 0; n2 < 2; n2++) {
                    int oc = col0 + wc*32 + n2*16 + (lane & 15);
                    float v = acc[m][n2][rr] + bias[oc];
                    dout[goff + oc] = res_src[goff + oc] + b2f(prj[wsoff + oc]) + v;
                }
            } else {
                #pragma unroll
                for (int n2 = 0; n2 < 2; n2++) {
                    int oc = col0 + wc*32 + n2*16 + (lane & 15);
                    float v = acc[m][n2][rr] + bias[oc];
                    if (MODE == 0) {
                        out[(long)t*Nn + oc] = f2b(v);
                    } else if (MODE == 1) {
                        int b_ = t / NW, n = t % NW;
                        if (oc < C_DIM) {
                            int head = oc >> 5, d = oc & 31;
                            out[(((long)b_*NH_ + head)*NW + n)*DH + d] = f2b(v * 0.17677669529663687f);
                        } else {
                            int och = oc - C_DIM;
                            int head = och >> 5, d = och & 31;
                            out2[(((long)b_*NH_ + head)*NW + n)*DH + d] = f2b(v);
                        }
                    } else if (MODE == 2) {
                        int b_ = t / NW, n = t % NW;
                        int head = oc >> 5, d = oc & 31;
                        out[(((long)b_*NH_ + head)*NW + n)*DH + d] = f2b(v);
                    } else {
                        float g2 = 0.5f * v * (1.0f + erff(v * 0.70710678118654752f));
                        out[(long)t*Nn + oc] = f2b(g2);
                    }
                }
            }
        }
    }
}

// ---------------------------------------------------------------------------
// MFMA attention: 1 wave per (window,head), 2 waves/block. (unchanged)
// ---------------------------------------------------------------------------
#define PSTR 72
#define VSTR 72

__global__ __launch_bounds__(128)
void attn_mfma(const bf16* __restrict__ qb, const bf16* __restrict__ kb,
               const bf16* __restrict__ vse, const bf16* __restrict__ vde,
               const float* __restrict__ rpb,
               bf16* __restrict__ ose, bf16* __restrict__ ode)
{
    __shared__ float rpbs[169*NH_];
    __shared__ short P[2][64][PSTR];
    __shared__ short VTs[2][32][VSTR];
    __shared__ short VTd[2][32][VSTR];
    int tid = threadIdx.x, wid = tid >> 6, lane = tid & 63;
    for (int i = tid; i < 169*NH_; i += 128) rpbs[i] = rpb[i];
    __syncthreads();

    int bh = blockIdx.x*2 + wid;
    int b_ = bh / NH_, head = bh % NH_;
    int w = b_ & (NWIN-1);
    int wh = w >> 3, ww = w & 7;
    long base = (long)bh * (NW*DH);
    int l15 = lane & 15, g = lane >> 4;

    short8 qf[4], kf[4];
    #pragma unroll
    for (int mi = 0; mi < 4; mi++) {
        int r = l15 + 16*mi; if (r > 48) r = 48;
        qf[mi] = *(const short8*)(qb + base + r*DH + 8*g);
    }
    #pragma unroll
    for (int ni = 0; ni < 4; ni++) {
        int r = l15 + 16*ni; if (r > 48) r = 48;
        kf[ni] = *(const short8*)(kb + base + r*DH + 8*g);
    }

    f32x4 sA[4][4];
    #pragma unroll
    for (int mi = 0; mi < 4; mi++)
        #pragma unroll
        for (int ni = 0; ni < 4; ni++)
            sA[mi][ni] = (f32x4){0.f,0.f,0.f,0.f};
    #pragma unroll
    for (int mi = 0; mi < 4; mi++)
        #pragma unroll
        for (int ni = 0; ni < 4; ni++)
            sA[mi][ni] = __builtin_amdgcn_mfma_f32_16x16x32_bf16(qf[mi], kf[ni], sA[mi][ni], 0, 0, 0);

    {
        int j0 = lane >> 2, seg = lane & 3;
        #pragma unroll
        for (int it = 0; it < 4; ++it) {
            int j = j0 + 16*it;
            short8 a = {0,0,0,0,0,0,0,0}, bv = {0,0,0,0,0,0,0,0};
            if (j < NW) {
                a  = *(const short8*)(vse + base + j*DH + seg*8);
                bv = *(const short8*)(vde + base + j*DH + seg*8);
            }
            #pragma unroll
            for (int s2 = 0; s2 < 8; ++s2) {
                VTs[wid][seg*8 + s2][j] = a[s2];
                VTd[wid][seg*8 + s2][j] = bv[s2];
            }
        }
    }

    int jv[4], j7r_[4], j7c_[4], jrh_[4], jrc_[4];
    #pragma unroll
    for (int ni = 0; ni < 4; ++ni) {
        int j = 16*ni + l15;
        jv[ni] = (j < NW);
        int a = (j*37) >> 8; int c = j - 7*a;
        j7r_[ni] = a; j7c_[ni] = c;
        int jh = wh*7 + a, jw = ww*7 + c;
        jrh_[ni] = (jh >= 49) + (jh >= 53);
        jrc_[ni] = (jw >= 49) + (jw >= 53);
    }

    #pragma unroll
    for (int mi = 0; mi < 4; mi++) {
        #pragma unroll
        for (int rr = 0; rr < 4; rr++) {
            int i = 16*mi + 4*g + rr;
            int iv = (i < NW);
            int i7r = (i*37) >> 8; int i7c = i - 7*i7r;
            int ih = wh*7 + i7r, iw = ww*7 + i7c;
            int irh = (ih >= 49) + (ih >= 53), irc = (iw >= 49) + (iw >= 53);
            float sv[4];
            #pragma unroll
            for (int ni = 0; ni < 4; ni++) {
                if (iv && jv[ni]) {
                    int ri = (i7r - j7r_[ni] + 6)*13 + (i7c - j7c_[ni] + 6);
                    float msk = (irh == jrh_[ni] && irc == jrc_[ni]) ? 0.f : -100.f;
                    sv[ni] = sA[mi][ni][rr] + rpbs[ri*NH_ + head] + msk;
                } else {
                    sv[ni] = -1e30f;
                }
            }
            float mx = fmaxf(fmaxf(sv[0], sv[1]), fmaxf(sv[2], sv[3]));
            mx = fmaxf(mx, __shfl_xor(mx, 1));
            mx = fmaxf(mx, __shfl_xor(mx, 2));
            mx = fmaxf(mx, __shfl_xor(mx, 4));
            mx = fmaxf(mx, __shfl_xor(mx, 8));
            float e[4], sum = 0.f;
            #pragma unroll
            for (int ni = 0; ni < 4; ni++) { e[ni] = __expf(sv[ni] - mx); sum += e[ni]; }
            sum += __shfl_xor(sum, 1);
            sum += __shfl_xor(sum, 2);
            sum += __shfl_xor(sum, 4);
            sum += __shfl_xor(sum, 8);
            float inv = 1.0f / sum;
            #pragma unroll
            for (int ni = 0; ni < 4; ni++)
                P[wid][i][16*ni + l15] = f2bs(e[ni] * inv);
        }
    }
    __syncthreads();

    f32x4 o1[4][2], o2[4][2];
    #pragma unroll
    for (int mi = 0; mi < 4; mi++)
        #pragma unroll
        for (int di = 0; di < 2; di++) {
            o1[mi][di] = (f32x4){0.f,0.f,0.f,0.f};
            o2[mi][di] = (f32x4){0.f,0.f,0.f,0.f};
        }
    #pragma unroll
    for (int mi = 0; mi < 4; mi++) {
        #pragma unroll
        for (int kk = 0; kk < 2; kk++) {
            short8 ap = *((short8*)&P[wid][16*mi + l15][kk*32 + 8*g]);
            #pragma unroll
            for (int di = 0; di < 2; di++) {
                short8 bv1 = *((short8*)&VTs[wid][16*di + l15][kk*32 + 8*g]);
                o1[mi][di] = __builtin_amdgcn_mfma_f32_16x16x32_bf16(ap, bv1, o1[mi][di], 0, 0, 0);
                short8 bv2 = *((short8*)&VTd[wid][16*di + l15][kk*32 + 8*g]);
                o2[mi][di] = __builtin_amdgcn_mfma_f32_16x16x32_bf16(ap, bv2, o2[mi][di], 0, 0, 0);
            }
        }
    }

    #pragma unroll
    for (int mi = 0; mi < 4; mi++) {
        #pragma unroll
        for (int rr = 0; rr < 4; rr++) {
            int i = 16*mi + 4*g + rr;
            if (i < NW) {
                long ob = ((long)b_*NW + i)*C_DIM + head*DH;
                #pragma unroll
                for (int di = 0; di < 2; di++) {
                    ose[ob + 16*di + l15] = f2b(o1[mi][di][rr]);
                    ode[ob + 16*di + l15] = f2b(o2[mi][di][rr]);
                }
            }
        }
    }
}

// ---------------------------------------------------------------------------
// Fused window-reverse + un-shift + residual + LN2 (xn only).
// ---------------------------------------------------------------------------
__global__ void resid_ln2_kernel(const float* __restrict__ se, const float* __restrict__ de,
                                 const bf16* __restrict__ pse, const bf16* __restrict__ pde,
                                 const float* __restrict__ g2s, const float* __restrict__ bb2s,
                                 const float* __restrict__ g2d, const float* __restrict__ bb2d,
                                 bf16* __restrict__ xns, bf16* __restrict__ xnd)
{
    int t = blockIdx.x, tid = threadIdx.x;
    int b = t / L_TOK, l = t % L_TOK;
    int h = l / WW2, wc = l % WW2;
    int hp = h - SS_;  if (hp < 0) hp += HH;
    int wp = wc - SS_; if (wp < 0) wp += WW2;
    int b_ = b*NWIN + (hp/WS_)*8 + (wp/WS_);
    int n  = (hp%WS_)*WS_ + (wp%WS_);
    long wsoff = ((long)b_*NW + n)*C_DIM;
    long off   = (long)t*C_DIM;
    {
        float x0 = se[off+tid]     + b2f(pse[wsoff+tid]);
        float x1 = se[off+tid+64]  + b2f(pse[wsoff+tid+64]);
        float x2 = se[off+tid+128] + b2f(pse[wsoff+tid+128]);
        float s  = wave_sum64(x0+x1+x2);
        float ss = wave_sum64(x0*x0 + x1*x1 + x2*x2);
        float mean = s * (1.0f/192.0f);
        float var  = ss * (1.0f/192.0f) - mean*mean;
        float rstd = rsqrtf(var + 1e-5f);
        xns[off+tid]     = f2b((x0-mean)*rstd*g2s[tid]     + bb2s[tid]);
        xns[off+tid+64]  = f2b((x1-mean)*rstd*g2s[tid+64]  + bb2s[tid+64]);
        xns[off+tid+128] = f2b((x2-mean)*rstd*g2s[tid+128] + bb2s[tid+128]);
    }
    {
        float x0 = de[off+tid]     + b2f(pde[wsoff+tid]);
        float x1 = de[off+tid+64]  + b2f(pde[wsoff+tid+64]);
        float x2 = de[off+tid+128] + b2f(pde[wsoff+tid+128]);
        float s  = wave_sum64(x0+x1+x2);
        float ss = wave_sum64(x0*x0 + x1*x1 + x2*x2);
        float mean = s * (1.0f/192.0f);
        float var  = ss * (1.0f/192.0f) - mean*mean;
        float rstd = rsqrtf(var + 1e-5f);
        xnd[off+tid]     = f2b((x0-mean)*rstd*g2d[tid]     + bb2d[tid]);
        xnd[off+tid+64]  = f2b((x1-mean)*rstd*g2d[tid+64]  + bb2d[tid+64]);
        xnd[off+tid+128] = f2b((x2-mean)*rstd*g2d[tid+128] + bb2d[tid+128]);
    }
}

// ---------------------------------------------------------------------------
extern "C" void kernel_launch(void* const* d_in, const int* in_sizes, int n_in,
                              void* d_out, int out_size, void* d_ws, size_t ws_size,
                              hipStream_t stream)
{
    const float* se     = (const float*)d_in[0];
    const float* de     = (const float*)d_in[1];
    const float* co     = (const float*)d_in[2];
    const float* n1se_g = (const float*)d_in[4];
    const float* n1se_b = (const float*)d_in[5];
    const float* n1de_g = (const float*)d_in[6];
    const float* n1de_b = (const float*)d_in[7];
    const float* rpb    = (const float*)d_in[8];
    const float* vse_w  = (const float*)d_in[9];
    const float* vse_b  = (const float*)d_in[10];
    const float* vde_w  = (const float*)d_in[11];
    const float* vde_b  = (const float*)d_in[12];
    const float* qk_w   = (const float*)d_in[13];
    const float* qk_b   = (const float*)d_in[14];
    const float* pse_w  = (const float*)d_in[15];
    const float* pse_b  = (const float*)d_in[16];
    const float* pde_w  = (const float*)d_in[17];
    const float* pde_b  = (const float*)d_in[18];
    const float* n2se_g = (const float*)d_in[19];
    const float* n2se_b = (const float*)d_in[20];
    const float* n2de_g = (const float*)d_in[21];
    const float* n2de_b = (const float*)d_in[22];
    const float* mse_w1 = (const float*)d_in[23];
    const float* mse_b1 = (const float*)d_in[24];
    const float* mse_w2 = (const float*)d_in[25];
    const float* mse_b2 = (const float*)d_in[26];
    const float* mde_w1 = (const float*)d_in[27];
    const float* mde_b1 = (const float*)d_in[28];
    const float* mde_w2 = (const float*)d_in[29];
    const float* mde_b2 = (const float*)d_in[30];

    char* ws = (char*)d_ws;
    const size_t U = (size_t)TOK * C_DIM * 2;   // 19,267,584 bytes
    bf16* sw  = (bf16*)(ws + 0*U);
    bf16* dw  = (bf16*)(ws + 1*U);
    bf16* cw  = (bf16*)(ws + 2*U);
    bf16* vse = (bf16*)(ws + 3*U);
    bf16* vde = (bf16*)(ws + 4*U);
    bf16* ode = (bf16*)(ws + 5*U);
    bf16* qb  = (bf16*)(ws + 0*U);
    bf16* kb  = (bf16*)(ws + 1*U);
    bf16* ose = (bf16*)(ws + 2*U);
    bf16* pse = (bf16*)(ws + 0*U);
    bf16* pde = (bf16*)(ws + 1*U);
    bf16* xns = (bf16*)(ws + 2*U);
    bf16* xnd = (bf16*)(ws + 3*U);
    bf16* hidse = (bf16*)(ws + 4*U);   // per-chunk hid, stream se (1 plane)
    bf16* hidde = (bf16*)(ws + 5*U);   // per-chunk hid, stream de (1 plane)
    bf16* hid = (bf16*)(ws + 4*U);     // fallback path scratch (2 planes)
    short* wfb = (short*)(ws + 6*U);   // 884,736 bf16 = 1.73 MB

    const bool frag = (ws_size >= 6*U + 884736ull*2ull);
    float* dout = (float*)d_out;
    const int CH = TOK/2;
    const int NX = TOK/128;   // 392

    if (frag)
        wconv<<<dim3(72, 9), 256, 0, stream>>>(vse_w, vde_w, qk_w, pse_w, pde_w,
                                               mse_w1, mse_w2, mde_w1, mde_w2, wfb);
    prep_kernel<<<TOK, 64, 0, stream>>>(se, de, co, n1se_g, n1se_b, n1de_g, n1de_b, sw, dw, cw);

    if (frag) {
        // V merged (both streams), K=384
        fgemm2<2,true,8><<<dim3(NX*2, 1), 384, 0, stream>>>(sw, cw, C_DIM, 2*C_DIM, wfb + 0, vse_b, C_DIM,
                                                            vse, nullptr,
                                                            dw, cw, wfb + 73728, vde_b, vde,
                                                            nullptr, nullptr, nullptr,
                                                            nullptr, nullptr, nullptr, 0, NX);
        // QK
        fgemm2<1,false,8><<<dim3(NX, 2), 384, 0, stream>>>(cw, cw, C_DIM, C_DIM, wfb + 147456, qk_b, 384,
                                                           qb, kb,
                                                           nullptr, nullptr, nullptr, nullptr, nullptr,
                                                           nullptr, nullptr, nullptr,
                                                           nullptr, nullptr, nullptr, 0, 0);
    } else {
        mgemm<2><<<dim3(TOK/BM, C_DIM/BN), 256, 0, stream>>>(sw, cw, C_DIM, 2*C_DIM, vse_w, vse_b, C_DIM,
                                                             vse, nullptr, nullptr, nullptr, 0, nullptr);
        mgemm<2><<<dim3(TOK/BM, C_DIM/BN), 256, 0, stream>>>(dw, cw, C_DIM, 2*C_DIM, vde_w, vde_b, C_DIM,
                                                             vde, nullptr, nullptr, nullptr, 0, nullptr);
        mgemm<1><<<dim3(TOK/BM, 384/BN), 256, 0, stream>>>(cw, cw, C_DIM, C_DIM, qk_w, qk_b, 384,
                                                           qb, kb, nullptr, nullptr, 0, nullptr);
    }

    attn_mfma<<<BWIN*NH_/2, 128, 0, stream>>>(qb, kb, vse, vde, rpb, ose, ode);

    if (frag) {
        // P merged (both streams)
        fgemm2<0,true,8><<<dim3(NX*2, 1), 384, 0, stream>>>(ose, ose, C_DIM, C_DIM, wfb + 221184, pse_b, C_DIM,
                                                            pse, nullptr,
                                                            ode, ode, wfb + 258048, pde_b, pde,
                                                            nullptr, nullptr, nullptr,
                                                            nullptr, nullptr, nullptr, 0, NX);
    } else {
        mgemm<0><<<dim3(TOK/BM, C_DIM/BN), 256, 0, stream>>>(ose, ose, C_DIM, C_DIM, pse_w, pse_b, C_DIM,
                                                             pse, nullptr, nullptr, nullptr, 0, nullptr);
        mgemm<0><<<dim3(TOK/BM, C_DIM/BN), 256, 0, stream>>>(ode, ode, C_DIM, C_DIM, pde_w, pde_b, C_DIM,
                                                             pde, nullptr, nullptr, nullptr, 0, nullptr);
    }

    resid_ln2_kernel<<<TOK, 64, 0, stream>>>(se, de, pse, pde,
                                             n2se_g, n2se_b, n2de_g, n2de_b, xns, xnd);

    if (frag) {
        // MLP: 4 chunks (TOK/4), each stream-DUAL: up(128-row) then down(64-row)
        const int C4 = TOK/4;            // 12544
        const int NU = C4/128;           // 98
        const int ND = C4/64;            // 196
        for (int c0 = 0; c0 < 4; c0++) {
            long off = (long)c0 * C4 * C_DIM;
            fgemm2<3,true,8><<<dim3(NU*2, 4), 384, 0, stream>>>(xns + off, xns + off, C_DIM, C_DIM,
                                                                wfb + 294912, mse_b1, HID_,
                                                                hidse, nullptr,
                                                                xnd + off, xnd + off, wfb + 589824, mde_b1, hidde,
                                                                nullptr, nullptr, nullptr,
                                                                nullptr, nullptr, nullptr, 0, NU);
            fgemm2<4,true,4><<<dim3(ND*2, 1), 384, 0, stream>>>(hidse, hidse, HID_, HID_,
                                                                wfb + 442368, mse_b2, C_DIM,
                                                                nullptr, nullptr,
                                                                hidde, hidde, wfb + 737280, mde_b2, nullptr,
                                                                se, pse, dout,
                                                                de, pde, dout + (size_t)TOK*C_DIM,
                                                                c0 * C4, ND);
        }
    } else {
        for (int c0 = 0; c0 < 2; c0++) {
            int t0 = c0 * CH;
            mgemm<3><<<dim3(CH/BM, HID_/BN), 256, 0, stream>>>(xns + (long)t0*C_DIM, xns + (long)t0*C_DIM,
                                                               C_DIM, C_DIM, mse_w1, mse_b1, HID_,
                                                               hid, nullptr, nullptr, nullptr, 0, nullptr);
            mgemm<4><<<dim3(CH/BM, C_DIM/BN), 256, 0, stream>>>(hid, hid, HID_, HID_, mse_w2, mse_b2, C_DIM,
                                                                nullptr, nullptr, se, pse, t0, dout);
        }
        for (int c0 = 0; c0 < 2; c0++) {
            int t0 = c0 * CH;
            mgemm<3><<<dim3(CH/BM, HID_/BN), 256, 0, stream>>>(xnd + (long)t0*C_DIM, xnd + (long)t0*C_DIM,
                                                               C_DIM, C_DIM, mde_w1, mde_b1, HID_,
                                                               hid, nullptr, nullptr, nullptr, 0, nullptr);
            mgemm<4><<<dim3(CH/BM, C_DIM/BN), 256, 0, stream>>>(hid, hid, HID_, HID_, mde_w2, mde_b2, C_DIM,
                                                                nullptr, nullptr, de, pde, t0,
                                                                dout + (size_t)TOK*C_DIM);
        }
    }
}